// Round 1
// baseline (472.072 us; speedup 1.0000x reference)
//
#include <hip/hip_runtime.h>
#include <hip/hip_bf16.h>
#include <math.h>

// ---------------------------------------------------------------------------
// Mamba2 forward, MI355X. Round 10: replace the in-proj GEMM (116.6us, 28%
// MfmaUtil, 2-barrier m97-structure) with a 256x256 8-phase counted-vmcnt
// schedule (T1 XCD swizzle + T2 LDS XOR swizzle + T3/T4 8-phase counted
// vmcnt(4) + T5 setprio). N padded 4480->4608 (18x256); epilogue guards
// n<4384 so zxbcdt layout and all downstream kernels are unchanged.
// Everything else byte-identical to round 9:
//   C0 cast, C1/C2 transpose, C3 colsum, K2 dt, K3 conv_silu, K4 chunk_state,
//   K5 scan, K6 y, K7 ln_reduce, K8 gemm_bt FOLD (old 128^2 path).
// ---------------------------------------------------------------------------

namespace {

constexpr int kB   = 2;
constexpr int kL   = 4096;
constexpr int kDI  = 2048;
constexpr int kDS  = 128;
constexpr int kNH  = 32;
constexpr int kHP  = 64;
constexpr int kDC  = 4;
constexpr int kCS  = 64;
constexpr int kNC  = kL / kCS;
constexpr int kDProj   = 2 * kDI + 2 * kDS + kNH;  // 4384
constexpr int kDProjP  = 4608;                     // 18*256 (8-phase tile pad)
constexpr int kConvDim = kDI + 2 * kDS;            // 2304
constexpr int kRows = kB * kL;                     // 8192
constexpr float kEps = 1e-5f;
constexpr int kTS = 136;   // LDS stride for [64][128] tiles
constexpr int kWS = 72;    // LDS stride for [64][64] tiles

typedef __bf16 bf16x8 __attribute__((ext_vector_type(8)));
typedef float f32x4 __attribute__((ext_vector_type(4)));
typedef unsigned short ushort8 __attribute__((ext_vector_type(8)));

__device__ inline float bu2f(unsigned short u) {
  union { unsigned int i; float f; } x; x.i = ((unsigned int)u) << 16; return x.f;
}
__device__ inline unsigned short f2bu(float f) {
  __hip_bfloat16 h = __float2bfloat16(f);
  return *reinterpret_cast<unsigned short*>(&h);
}

__device__ inline void store_out(float* C, size_t i, float v) { C[i] = v; }
__device__ inline void store_out(unsigned short* C, size_t i, float v) { C[i] = f2bu(v); }

__device__ inline void gld_lds16(const unsigned short* g, unsigned short* l) {
  __builtin_amdgcn_global_load_lds(
      (const __attribute__((address_space(1))) unsigned int*)g,
      (__attribute__((address_space(3))) unsigned int*)l, 16, 0, 0);
}

// ---- C0: cast fp32 -> bf16
__global__ void cast_kernel(const float4* __restrict__ in, ushort4* __restrict__ out, int n4) {
  int i = blockIdx.x * 256 + threadIdx.x;
  if (i >= n4) return;
  float4 v = in[i];
  ushort4 o;
  o.x = f2bu(v.x); o.y = f2bu(v.y); o.z = f2bu(v.z); o.w = f2bu(v.w);
  out[i] = o;
}

// ---- C1/C2: transpose + cast (+optional per-row scale)
__global__ void transpose_cast(const float* __restrict__ in, unsigned short* __restrict__ out,
                               int R, int C, const float* __restrict__ scale) {
  __shared__ float t[32][33];
  const int c0 = blockIdx.x * 32;
  const int r0 = blockIdx.y * 32;
  const int tx = threadIdx.x & 31, ty = threadIdx.x >> 5;
  for (int rr = ty; rr < 32; rr += 8) {
    int c = c0 + tx;
    float v = (c < C) ? in[(size_t)(r0 + rr) * C + c] : 0.f;
    if (scale) v *= scale[r0 + rr];
    t[rr][tx] = v;
  }
  __syncthreads();
  for (int cc = ty; cc < 32; cc += 8) {
    int orow = c0 + cc;
    out[(size_t)orow * R + r0 + tx] = f2bu(t[tx][cc]);
  }
}

// ---- C3: t1[n] = sum_k w[k]*W2[k][n], t2[n] = sum_k b[k]*W2[k][n]
__global__ void colsum_kernel(const float* __restrict__ W2, const float* __restrict__ wv,
                              const float* __restrict__ bv,
                              float* __restrict__ t1, float* __restrict__ t2) {
  __shared__ float p1[4][64], p2[4][64];
  const int nl = threadIdx.x & 63;
  const int ks = threadIdx.x >> 6;
  const int n = blockIdx.x * 64 + nl;
  float s1 = 0.f, s2 = 0.f;
  for (int k = ks * 512; k < ks * 512 + 512; k++) {
    float v = W2[(size_t)k * 1024 + n];
    s1 += wv[k] * v;
    s2 += bv[k] * v;
  }
  p1[ks][nl] = s1; p2[ks][nl] = s2;
  __syncthreads();
  if (threadIdx.x < 64) {
    t1[blockIdx.x * 64 + threadIdx.x] =
        p1[0][threadIdx.x] + p1[1][threadIdx.x] + p1[2][threadIdx.x] + p1[3][threadIdx.x];
    t2[blockIdx.x * 64 + threadIdx.x] =
        p2[0][threadIdx.x] + p2[1][threadIdx.x] + p2[2][threadIdx.x] + p2[3][threadIdx.x];
  }
}

// ---- K1: 256x256 8-phase bf16 GEMM, C[m][n] = sum_k A[m][k]*Bt[n][k].
// 8 waves (2M x 4N), wave tile 128x64, BK=64, double-buffered 128KB LDS.
// Halves: A-h0 = tile rows {0-63,128-191}, A-h1 = {64-127,192-255};
//         B-h0 = rows == [0,32) mod 64, B-h1 = rows == [32,64) mod 64.
// Quadrant-phase q reads A-half (q>>1), B-half (q&1); each phase stages
// exactly one DEAD half-tile of a future K-tile; vmcnt(4) only at tile
// boundaries (never 0 in steady state). XOR swizzle slot^=(row&7) applied
// to the GLOBAL source (LDS dest linear, rule #21) and to the ds_read addr.
#define STG_A(bs, h, t)                                                         \
  gld_lds16(srcA[h][0] + (t) * 64, &sA[bs][(h) * 8192 + wave * 1024]);          \
  gld_lds16(srcA[h][1] + (t) * 64, &sA[bs][(h) * 8192 + wave * 1024 + 512]);
#define STG_B(bs, h, t)                                                         \
  gld_lds16(srcB[h][0] + (t) * 64, &sB[bs][(h) * 8192 + wave * 1024]);          \
  gld_lds16(srcB[h][1] + (t) * 64, &sB[bs][(h) * 8192 + wave * 1024 + 512]);

#define PHASE(q_, curA_, curB_, STAGE_STMT, TAIL_STMT)                          \
  {                                                                             \
    const int ha_ = (q_) >> 1, hb_ = (q_) & 1;                                  \
    bf16x8 af_[4][2], bf_[2][2];                                                \
    _Pragma("unroll")                                                           \
    for (int i_ = 0; i_ < 4; i_++) {                                            \
      af_[i_][0] = *(const bf16x8*)&(curA_)[ha_ * 8192 + rbaseA + i_ * 1024 + sk0]; \
      af_[i_][1] = *(const bf16x8*)&(curA_)[ha_ * 8192 + rbaseA + i_ * 1024 + sk1]; \
    }                                                                           \
    _Pragma("unroll")                                                           \
    for (int j_ = 0; j_ < 2; j_++) {                                            \
      bf_[j_][0] = *(const bf16x8*)&(curB_)[hb_ * 8192 + rbaseB + j_ * 1024 + sk0]; \
      bf_[j_][1] = *(const bf16x8*)&(curB_)[hb_ * 8192 + rbaseB + j_ * 1024 + sk1]; \
    }                                                                           \
    STAGE_STMT                                                                  \
    __builtin_amdgcn_s_barrier();                                               \
    asm volatile("s_waitcnt lgkmcnt(0)" ::: "memory");                          \
    __builtin_amdgcn_sched_barrier(0);                                          \
    __builtin_amdgcn_s_setprio(1);                                              \
    _Pragma("unroll")                                                           \
    for (int i_ = 0; i_ < 4; i_++)                                              \
      _Pragma("unroll")                                                         \
      for (int j_ = 0; j_ < 2; j_++) {                                          \
        acc[ha_ * 4 + i_][hb_ * 2 + j_] = __builtin_amdgcn_mfma_f32_16x16x32_bf16( \
            af_[i_][0], bf_[j_][0], acc[ha_ * 4 + i_][hb_ * 2 + j_], 0, 0, 0);  \
        acc[ha_ * 4 + i_][hb_ * 2 + j_] = __builtin_amdgcn_mfma_f32_16x16x32_bf16( \
            af_[i_][1], bf_[j_][1], acc[ha_ * 4 + i_][hb_ * 2 + j_], 0, 0, 0);  \
      }                                                                         \
    __builtin_amdgcn_s_setprio(0);                                              \
    __builtin_amdgcn_sched_barrier(0);                                          \
    TAIL_STMT                                                                   \
    __builtin_amdgcn_s_barrier();                                               \
  }

__global__ __launch_bounds__(512, 2) void gemm_bt_8p(
    const unsigned short* __restrict__ A, const unsigned short* __restrict__ Bt,
    unsigned short* __restrict__ C, int Nreal) {
  constexpr int K = 1024, NT = 16;   // K-tiles of BK=64
  constexpr int GX = kDProjP / 256;  // 18
  constexpr int NWG = GX * (kRows / 256);  // 576, %8 == 0
  __shared__ __align__(16) unsigned short sA[2][16384];
  __shared__ __align__(16) unsigned short sB[2][16384];
  const int tid = (int)threadIdx.x;
  const int wave = tid >> 6, lane = tid & 63;
  const int wm = wave >> 2, wn = wave & 3;
  // T1: bijective XCD swizzle (NWG % 8 == 0)
  const int orig = (int)blockIdx.y * GX + (int)blockIdx.x;
  const int swz = (orig & 7) * (NWG / 8) + (orig >> 3);
  const int m0 = (swz / GX) * 256;
  const int n0 = (swz % GX) * 256;
  // staging source pointers: pre-swizzled global addr, linear LDS dest
  const int l8 = lane >> 3, s8 = lane & 7;
  const unsigned short* srcA[2][2];
  const unsigned short* srcB[2][2];
#pragma unroll
  for (int h = 0; h < 2; h++)
#pragma unroll
    for (int cc = 0; cc < 2; cc++) {
      const int lrow = (wave * 2 + cc) * 8 + l8;       // row within half [0,128)
      const int slot = s8 ^ (lrow & 7);                // inverse of read swizzle
      const int rA = (lrow & 63) + h * 64 + ((lrow >> 6) << 7);
      const int rB = (lrow & 31) + h * 32 + ((lrow >> 5) << 6);
      srcA[h][cc] = A + (size_t)(m0 + rA) * K + slot * 8;
      srcB[h][cc] = Bt + (size_t)(n0 + rB) * K + slot * 8;
    }
  // fragment read offsets (swizzled)
  const int fr = lane & 15, c4 = lane >> 4;
  const int sk0 = (c4 ^ (fr & 7)) * 8;
  const int sk1 = ((4 | c4) ^ (fr & 7)) * 8;
  const int rbaseA = (wm * 64 + fr) * 64;
  const int rbaseB = (wn * 32 + fr) * 64;
  f32x4 acc[8][4] = {};
  unsigned short* const a0 = &sA[0][0];
  unsigned short* const a1 = &sA[1][0];
  unsigned short* const b0 = &sB[0][0];
  unsigned short* const b1 = &sB[1][0];
  // prologue: tile0 complete + tile1 h0 halves; vmcnt(4) leaves tile1-h0 in flight
  STG_A(0, 0, 0) STG_B(0, 0, 0) STG_A(0, 1, 0) STG_B(0, 1, 0)
  STG_A(1, 0, 1) STG_B(1, 0, 1)
  asm volatile("s_waitcnt vmcnt(4)" ::: "memory");
  __builtin_amdgcn_s_barrier();
  for (int u = 0; u < NT; u += 2) {
    const int t1 = u + 1, t2 = u + 2, t3 = u + 3;
    // tile u (even): cur = buf0, next = buf1
    PHASE(0, a0, b0, { STG_A(1, 1, t1) }, {})
    PHASE(1, a0, b0, { STG_B(1, 1, t1) }, {})
    PHASE(2, a0, b0, { if (t2 < NT) { STG_A(0, 0, t2) } }, {})
    PHASE(3, a0, b0, { if (t2 < NT) { STG_B(0, 0, t2) } },
          { if (t2 < NT) { asm volatile("s_waitcnt vmcnt(4)" ::: "memory"); }
            else { asm volatile("s_waitcnt vmcnt(0)" ::: "memory"); } })
    // tile u+1 (odd): cur = buf1, next = buf0
    PHASE(0, a1, b1, { if (t2 < NT) { STG_A(0, 1, t2) } }, {})
    PHASE(1, a1, b1, { if (t2 < NT) { STG_B(0, 1, t2) } }, {})
    PHASE(2, a1, b1, { if (t3 < NT) { STG_A(1, 0, t3) } }, {})
    PHASE(3, a1, b1, { if (t3 < NT) { STG_B(1, 0, t3) } },
          { if (t3 < NT) { asm volatile("s_waitcnt vmcnt(4)" ::: "memory"); }
            else { asm volatile("s_waitcnt vmcnt(0)" ::: "memory"); } })
  }
  // epilogue: acc[ii][jj] -> m offset (ii>>2)*64 + (ii&3)*16, n offset (jj>>1)*32 + (jj&1)*16
  const int crow = c4 * 4;
#pragma unroll
  for (int ii = 0; ii < 8; ii++) {
    const int mbase = m0 + wm * 128 + (ii >> 2) * 64 + (ii & 3) * 16 + crow;
#pragma unroll
    for (int jj = 0; jj < 4; jj++) {
      const int n = n0 + wn * 64 + (jj >> 1) * 32 + (jj & 1) * 16 + fr;
      if (n < Nreal) {
#pragma unroll
        for (int r = 0; r < 4; r++)
          C[(size_t)(mbase + r) * Nreal + n] = f2bu(acc[ii][jj][r]);
      }
    }
  }
}
#undef PHASE
#undef STG_A
#undef STG_B

// ---- old MFMA GEMM with XOR-swizzled LDS (kept for the FOLD output GEMM).
template <typename OutT, bool FOLD>
__global__ __launch_bounds__(256) void gemm_bt(const unsigned short* __restrict__ A,
                                               const unsigned short* __restrict__ Bt,
                                               OutT* __restrict__ C, int M, int N, int K,
                                               const float* __restrict__ mu,
                                               const float* __restrict__ rstd,
                                               const float* __restrict__ t1,
                                               const float* __restrict__ t2) {
  __shared__ __align__(16) unsigned short As[128 * 32];
  __shared__ __align__(16) unsigned short Bs[128 * 32];
  const int tid = threadIdx.x;
  const int wave = tid >> 6, lane = tid & 63;
  const int m0 = blockIdx.y * 128, n0 = blockIdx.x * 128;
  const int wr = (wave >> 1) * 64, wc = (wave & 1) * 64;
  const int st_row = lane >> 2;
  const int st_col = (((lane & 3) ^ ((st_row >> 1) & 3))) * 8;  // XOR swizzle
  const unsigned short* pA[2];
  const unsigned short* pB[2];
  unsigned short* lA[2];
  unsigned short* lB[2];
#pragma unroll
  for (int r = 0; r < 2; r++) {
    int q = wave * 2 + r;
    pA[r] = A + (size_t)(m0 + q * 16 + st_row) * K + st_col;
    pB[r] = Bt + (size_t)(n0 + q * 16 + st_row) * K + st_col;
    lA[r] = &As[q * 512];
    lB[r] = &Bs[q * 512];
  }
  const int frag_row = lane & 15;
  const int rk = (((lane >> 4) ^ ((frag_row >> 1) & 3))) * 8;
  f32x4 acc[4][4] = {};
  for (int k0 = 0; k0 < K; k0 += 32) {
#pragma unroll
    for (int r = 0; r < 2; r++) {
      gld_lds16(pA[r] + k0, lA[r]);
      gld_lds16(pB[r] + k0, lB[r]);
    }
    asm volatile("s_waitcnt vmcnt(0)" ::: "memory");
    __syncthreads();
    bf16x8 af[4], bfr[4];
#pragma unroll
    for (int i = 0; i < 4; i++)
      af[i] = *(const bf16x8*)&As[(wr + i * 16 + frag_row) * 32 + rk];
#pragma unroll
    for (int j = 0; j < 4; j++)
      bfr[j] = *(const bf16x8*)&Bs[(wc + j * 16 + frag_row) * 32 + rk];
#pragma unroll
    for (int i = 0; i < 4; i++)
#pragma unroll
      for (int j = 0; j < 4; j++)
        acc[i][j] = __builtin_amdgcn_mfma_f32_16x16x32_bf16(af[i], bfr[j], acc[i][j], 0, 0, 0);
    __syncthreads();
  }
  const int crow = (lane >> 4) * 4;
  const int ccol = lane & 15;
#pragma unroll
  for (int i = 0; i < 4; i++) {
#pragma unroll
    for (int j = 0; j < 4; j++) {
      int n = n0 + wc + j * 16 + ccol;
      if (n < N) {
        float c1 = FOLD ? t1[n] : 0.f;
        float c2 = FOLD ? t2[n] : 0.f;
#pragma unroll
        for (int r = 0; r < 4; r++) {
          int m = m0 + wr + i * 16 + crow + r;
          float v = acc[i][j][r];
          if (FOLD) v = rstd[m] * (v - mu[m] * c1) + c2;
          store_out(C, (size_t)m * N + n, v);
        }
      }
    }
  }
}

// ---- K2: dt = softplus(dt_raw + dt_bias)
__global__ void dt_kernel(const unsigned short* __restrict__ zxbcdt,
                          const float* __restrict__ dt_bias,
                          float* __restrict__ dtbuf) {
  int idx = blockIdx.x * 256 + threadIdx.x;
  if (idx >= kRows * kNH) return;
  int row = idx >> 5, h = idx & 31;
  float x = bu2f(zxbcdt[(size_t)row * kDProj + (kDProj - kNH) + h]) + dt_bias[h];
  dtbuf[idx] = (x > 15.f) ? x : log1pf(expf(x));
}

// ---- K3: causal depthwise conv (k=4) + SiLU, 8 rows x 4 cols per thread
__global__ void conv_silu_kernel(const unsigned short* __restrict__ zxbcdt,
                                 const float* __restrict__ conv_w,
                                 const float* __restrict__ conv_b,
                                 unsigned short* __restrict__ xbc_act) {
  int c4 = blockIdx.x * 256 + threadIdx.x;
  if (c4 >= kConvDim / 4) return;
  const int c = c4 * 4;
  const int r0 = blockIdx.y * 8;
  const int l0 = r0 & (kL - 1);
  float4 w[4];
  float bias[4];
#pragma unroll
  for (int q = 0; q < 4; q++) {
    w[q] = ((const float4*)conv_w)[c + q];
    bias[q] = conv_b[c + q];
  }
  float v[11][4];
#pragma unroll
  for (int i = 0; i < 11; i++) {
    int l = l0 - 3 + i;
    if (l >= 0) {
      ushort4 t = *(const ushort4*)&zxbcdt[(size_t)(r0 - 3 + i) * kDProj + kDI + c];
      v[i][0] = bu2f(t.x); v[i][1] = bu2f(t.y); v[i][2] = bu2f(t.z); v[i][3] = bu2f(t.w);
    } else {
      v[i][0] = v[i][1] = v[i][2] = v[i][3] = 0.f;
    }
  }
#pragma unroll
  for (int j = 0; j < 8; j++) {
    ushort4 o;
    unsigned short* op = (unsigned short*)&o;
#pragma unroll
    for (int q = 0; q < 4; q++) {
      float a = bias[q] + v[j][q] * w[q].x + v[j + 1][q] * w[q].y +
                v[j + 2][q] * w[q].z + v[j + 3][q] * w[q].w;
      op[q] = f2bu(a / (1.f + expf(-a)));
    }
    *(ushort4*)&xbc_act[(size_t)(r0 + j) * kConvDim + c] = o;
  }
}

// ---- K4: per-(b,chunk,head) end-of-chunk state via MFMA
__global__ __launch_bounds__(256) void chunk_state_kernel(
    const unsigned short* __restrict__ xbc_act,
    const float* __restrict__ dtbuf,
    const float* __restrict__ A_log,
    unsigned short* __restrict__ states,
    float* __restrict__ asum) {
  const int id = blockIdx.x;
  const int h = id & 31;
  const int c = (id >> 5) & (kNC - 1);
  const int b = id >> 11;
  const int tid = threadIdx.x;
  const int wave = tid >> 6, lane = tid & 63;
  __shared__ __align__(16) unsigned short sBT[kDS * kWS];
  __shared__ __align__(16) unsigned short sxd[kCS * kWS];
  __shared__ float s_dt[kCS];
  __shared__ float s_acum[kCS];
  const int l0 = b * kL + c * kCS;
  if (tid < kCS) s_dt[tid] = dtbuf[(size_t)(l0 + tid) * kNH + h];
  __syncthreads();
  if (tid == 0) {
    float A = -expf(A_log[h]);
    float run = 0.f;
    for (int s = 0; s < kCS; s++) { run += A * s_dt[s]; s_acum[s] = run; }
    asum[id] = run;
  }
  __syncthreads();
  const float total = s_acum[kCS - 1];
  for (int e = tid; e < kCS * kDS; e += 256) {
    int s = e >> 7, n = e & 127;
    sBT[n * kWS + s] = xbc_act[(size_t)(l0 + s) * kConvDim + kDI + n];
  }
  for (int e = tid; e < kCS * kHP; e += 256) {
    int s = e >> 6, p = e & 63;
    float xv = bu2f(xbc_act[(size_t)(l0 + s) * kConvDim + h * kHP + p]);
    sxd[p * kWS + s] = f2bu(xv * s_dt[s] * expf(total - s_acum[s]));
  }
  __syncthreads();
  const int arow = wave * 16 + (lane & 15);
  const int fk = (lane >> 4) * 8;
  f32x4 acc[8] = {};
#pragma unroll
  for (int kk = 0; kk < 2; kk++) {
    bf16x8 a = *(const bf16x8*)&sxd[arow * kWS + kk * 32 + fk];
#pragma unroll
    for (int j = 0; j < 8; j++) {
      bf16x8 bb = *(const bf16x8*)&sBT[(j * 16 + (lane & 15)) * kWS + kk * 32 + fk];
      acc[j] = __builtin_amdgcn_mfma_f32_16x16x32_bf16(a, bb, acc[j], 0, 0, 0);
    }
  }
  const int prow = wave * 16 + (lane >> 4) * 4;
  const int ncol = lane & 15;
  size_t base = (size_t)id * (kHP * kDS);
#pragma unroll
  for (int j = 0; j < 8; j++)
#pragma unroll
    for (int r = 0; r < 4; r++)
      states[base + (size_t)(prow + r) * kDS + j * 16 + ncol] = f2bu(acc[j][r]);
}

// ---- K5: sequential inter-chunk scan with software prefetch
__global__ void scan_kernel(unsigned short* __restrict__ states,
                            const float* __restrict__ asum) {
  const int blk = blockIdx.x;
  const int seg = blk & 7;
  const int bh = blk >> 3;
  const int h = bh & 31, b = bh >> 5;
  const int e4 = seg * 256 + threadIdx.x;
  const size_t cstride = (size_t)kNH * 2048;            // ushort4 units per chunk
  ushort4* p = (ushort4*)states + ((size_t)(b * kNC) * kNH + h) * 2048 + e4;
  const float* ap = asum + (b * kNC) * kNH + h;
  float c0 = 0.f, c1 = 0.f, c2 = 0.f, c3 = 0.f;
  ushort4 t = p[0];
  float dec = expf(ap[0]);
  for (int c = 0; c < kNC; c++) {
    ushort4 tn = t;
    float decn = dec;
    if (c + 1 < kNC) {                                  // prefetch next chunk
      tn = p[(size_t)(c + 1) * cstride];
      decn = expf(ap[(c + 1) * kNH]);
    }
    ushort4 o;
    o.x = f2bu(c0); o.y = f2bu(c1); o.z = f2bu(c2); o.w = f2bu(c3);
    p[(size_t)c * cstride] = o;
    c0 = c0 * dec + bu2f(t.x);
    c1 = c1 * dec + bu2f(t.y);
    c2 = c2 * dec + bu2f(t.z);
    c3 = c3 * dec + bu2f(t.w);
    t = tn; dec = decn;
  }
}

// ---- K6: intra-chunk Y, 4 heads/block (round-6 version: Sin staged via LDS)
__global__ __launch_bounds__(256) void y_kernel(
    const unsigned short* __restrict__ xbc_act,
    const unsigned short* __restrict__ zxbcdt,
    const unsigned short* __restrict__ states_in,
    const float* __restrict__ dtbuf,
    const float* __restrict__ A_log,
    unsigned short* __restrict__ ybuf,
    float* __restrict__ pS, float* __restrict__ pQ) {
  const int id = blockIdx.x;                 // (b*NC + c)*8 + hg
  const int hg = id & 7;
  const int c = (id >> 3) & (kNC - 1);
  const int b = id >> 9;
  const int tid = threadIdx.x;
  const int wave = tid >> 6, lane = tid & 63;
  __shared__ __align__(16) unsigned short sC[kCS * kTS];
  __shared__ __align__(16) unsigned short sB[kCS * kTS];
  __shared__ __align__(16) unsigned short sxd[kCS * kWS];
  __shared__ __align__(16) unsigned short sW[kCS * kWS];
  __shared__ float s_dt[4][kCS];
  __shared__ float s_acum[4][kCS];
  const int l0 = b * kL + c * kCS;
  {
    int hh = tid >> 6, s = tid & 63;
    s_dt[hh][s] = dtbuf[(size_t)(l0 + s) * kNH + hg * 4 + hh];
  }
  __syncthreads();
  if (tid < 4) {
    float A = -expf(A_log[hg * 4 + tid]);
    float run = 0.f;
    for (int s = 0; s < kCS; s++) { run += A * s_dt[tid][s]; s_acum[tid][s] = run; }
  }
  for (int e = tid; e < kCS * 16; e += 256) {
    int row = e >> 4, c8 = (e & 15) * 8;
    size_t rb = (size_t)(l0 + row) * kConvDim;
    *(ushort8*)&sB[row * kTS + c8] = *(const ushort8*)&xbc_act[rb + kDI + c8];
    *(ushort8*)&sC[row * kTS + c8] = *(const ushort8*)&xbc_act[rb + kDI + kDS + c8];
  }
  __syncthreads();
  const int arow = wave * 16 + (lane & 15);
  const int fk = (lane >> 4) * 8;
  // G[l][s] = C . B^T  (K=128) — head-independent, once per block
  f32x4 accG[4] = {};
#pragma unroll
  for (int kk = 0; kk < 4; kk++) {
    bf16x8 a = *(const bf16x8*)&sC[arow * kTS + kk * 32 + fk];
#pragma unroll
    for (int j = 0; j < 4; j++) {
      bf16x8 bb = *(const bf16x8*)&sB[(j * 16 + (lane & 15)) * kTS + kk * 32 + fk];
      accG[j] = __builtin_amdgcn_mfma_f32_16x16x32_bf16(a, bb, accG[j], 0, 0, 0);
    }
  }
  const int lrow = wave * 16 + (lane >> 4) * 4;
  const size_t sbase = (size_t)((b * kNC + c) * kNH) * (kHP * kDS);
  float rS[4] = {}, rQ[4] = {};
  for (int hh = 0; hh < 4; hh++) {
    const int h = hg * 4 + hh;
    __syncthreads();   // prior iteration (or G) done reading sB/sxd/sW
    // stage xd^T for this head
    for (int e = tid; e < kCS * kHP; e += 256) {
      int s = e >> 6, p = e & 63;
      float xv = bu2f(xbc_act[(size_t)(l0 + s) * kConvDim + h * kHP + p]);
      sxd[p * kWS + s] = f2bu(xv * s_dt[hh][s]);
    }
    // W = mask(G)*decay  (wave-local strip)
#pragma unroll
    for (int j = 0; j < 4; j++) {
      int scol = j * 16 + (lane & 15);
      float as = s_acum[hh][scol];
#pragma unroll
      for (int r = 0; r < 4; r++) {
        int l = lrow + r;
        float w = (scol <= l) ? accG[j][r] * expf(s_acum[hh][l] - as) : 0.f;
        sW[l * kWS + scol] = f2bu(w);
      }
    }
    // stage Sin[p][n] for this head into sB
    for (int e = tid; e < kCS * 16; e += 256) {
      int row = e >> 4, c8 = (e & 15) * 8;
      *(ushort8*)&sB[row * kTS + c8] =
          *(const ushort8*)&states_in[sbase + (size_t)h * (kHP * kDS) + row * kDS + c8];
    }
    __syncthreads();
    // Yd = W . xd^T  (K=64)
    f32x4 accY[4] = {};
#pragma unroll
    for (int kk = 0; kk < 2; kk++) {
      bf16x8 a = *(const bf16x8*)&sW[arow * kWS + kk * 32 + fk];
#pragma unroll
      for (int j = 0; j < 4; j++) {
        bf16x8 bb = *(const bf16x8*)&sxd[(j * 16 + (lane & 15)) * kWS + kk * 32 + fk];
        accY[j] = __builtin_amdgcn_mfma_f32_16x16x32_bf16(a, bb, accY[j], 0, 0, 0);
      }
    }
    // Yoff = C . Sin^T  (K=128)
    f32x4 accO[4] = {};
#pragma unroll
    for (int kk = 0; kk < 4; kk++) {
      bf16x8 a = *(const bf16x8*)&sC[arow * kTS + kk * 32 + fk];
#pragma unroll
      for (int j = 0; j < 4; j++) {
        bf16x8 bb = *(const bf16x8*)&sB[(j * 16 + (lane & 15)) * kTS + kk * 32 + fk];
        accO[j] = __builtin_amdgcn_mfma_f32_16x16x32_bf16(a, bb, accO[j], 0, 0, 0);
      }
    }
#pragma unroll
    for (int r = 0; r < 4; r++) {
      int l = lrow + r;
      float el = expf(s_acum[hh][l]);
      size_t zrow = (size_t)(l0 + l) * kDProj + h * kHP;
      size_t yrow = (size_t)(l0 + l) * kDI + h * kHP;
#pragma unroll
      for (int j = 0; j < 4; j++) {
        int p = j * 16 + (lane & 15);
        float yv = accY[j][r] + el * accO[j][r];
        float z = bu2f(zxbcdt[zrow + p]);
        yv *= z / (1.f + expf(-z));
        rS[r] += yv;
        rQ[r] += yv * yv;
        ybuf[yrow + p] = f2bu(yv);
      }
    }
  }
#pragma unroll
  for (int m = 1; m < 16; m <<= 1) {
#pragma unroll
    for (int r = 0; r < 4; r++) {
      rS[r] += __shfl_xor(rS[r], m);
      rQ[r] += __shfl_xor(rQ[r], m);
    }
  }
  if ((lane & 15) == 0) {
#pragma unroll
    for (int r = 0; r < 4; r++) {
      int row = l0 + lrow + r;
      pS[(size_t)row * 8 + hg] = rS[r];
      pQ[(size_t)row * 8 + hg] = rQ[r];
    }
  }
}

// ---- K7: finalize LN stats from per-block partials
__global__ void ln_reduce(const float* __restrict__ pS, const float* __restrict__ pQ,
                          float* __restrict__ mu, float* __restrict__ rstd) {
  int row = blockIdx.x * 256 + threadIdx.x;
  if (row >= kRows) return;
  float s = 0.f, q = 0.f;
#pragma unroll
  for (int i = 0; i < 8; i++) { s += pS[(size_t)row * 8 + i]; q += pQ[(size_t)row * 8 + i]; }
  float m = s / kDI;
  mu[row] = m;
  rstd[row] = rsqrtf(q / kDI - m * m + kEps);
}

}  // namespace

extern "C" void kernel_launch(void* const* d_in, const int* in_sizes, int n_in,
                              void* d_out, int out_size, void* d_ws, size_t ws_size,
                              hipStream_t stream) {
  const float* u       = (const float*)d_in[0];
  const float* W_in    = (const float*)d_in[1];
  const float* conv_w  = (const float*)d_in[2];
  const float* conv_b  = (const float*)d_in[3];
  const float* dt_bias = (const float*)d_in[4];
  const float* A_log   = (const float*)d_in[5];
  const float* norm_w  = (const float*)d_in[6];
  const float* norm_b  = (const float*)d_in[7];
  const float* W_out   = (const float*)d_in[8];
  float* out = (float*)d_out;

  char* ws = (char*)d_ws;
  size_t off = 0;
  auto alloc = [&](size_t bytes) {
    void* p = ws + off;
    off += (bytes + 255) & ~(size_t)255;
    return p;
  };
  unsigned short* zxbcdt = (unsigned short*)alloc((size_t)kRows * kDProj * 2);        // 71.8 MB
  unsigned short* xbc    = (unsigned short*)alloc((size_t)kRows * kConvDim * 2);      // 37.7 MB
  float* dtb             = (float*)alloc((size_t)kRows * kNH * 4);                    //  1.0 MB
  float* asum            = (float*)alloc((size_t)kB * kNC * kNH * 4);                 // 16 KB
  unsigned short* A1     = (unsigned short*)alloc((size_t)kRows * 1024 * 2);          // 16.8 MB
  unsigned short* Bt1    = (unsigned short*)alloc((size_t)kDProjP * 1024 * 2);        //  9.4 MB
  unsigned short* states = (unsigned short*)alloc((size_t)kB * kNC * kNH * kHP * kDS * 2); // 67.1 MB
  unsigned short* Bt2    = (unsigned short*)alloc((size_t)1024 * kDI * 2);            //  4.2 MB
  unsigned short* ybuf   = (unsigned short*)alloc((size_t)kRows * kDI * 2);           // 33.6 MB
  float* mu              = (float*)alloc((size_t)kRows * 4);
  float* rstd            = (float*)alloc((size_t)kRows * 4);
  float* t1              = (float*)alloc(1024 * 4);
  float* t2              = (float*)alloc(1024 * 4);
  float* pS              = (float*)alloc((size_t)kRows * 8 * 4);                      // 256 KB
  float* pQ              = (float*)alloc((size_t)kRows * 8 * 4);                      // 256 KB
  (void)ws_size; (void)in_sizes; (void)n_in; (void)out_size;

  cast_kernel<<<(kRows * 1024 / 4 + 255) / 256, 256, 0, stream>>>(
      (const float4*)u, (ushort4*)A1, kRows * 1024 / 4);
  transpose_cast<<<dim3(kDProjP / 32, 1024 / 32), 256, 0, stream>>>(
      W_in, Bt1, 1024, kDProj, nullptr);
  transpose_cast<<<dim3(1024 / 32, 2048 / 32), 256, 0, stream>>>(
      W_out, Bt2, 2048, 1024, norm_w);
  colsum_kernel<<<16, 256, 0, stream>>>(W_out, norm_w, norm_b, t1, t2);
  gemm_bt_8p<<<dim3(kDProjP / 256, kRows / 256), 512, 0, stream>>>(
      A1, Bt1, zxbcdt, kDProj);
  dt_kernel<<<(kRows * kNH + 255) / 256, 256, 0, stream>>>(zxbcdt, dt_bias, dtb);
  conv_silu_kernel<<<dim3(3, kRows / 8), 256, 0, stream>>>(zxbcdt, conv_w, conv_b, xbc);
  chunk_state_kernel<<<kB * kNC * kNH, 256, 0, stream>>>(xbc, dtb, A_log, states, asum);
  scan_kernel<<<kB * kNH * 8, 256, 0, stream>>>(states, asum);
  y_kernel<<<kB * kNC * 8, 256, 0, stream>>>(xbc, zxbcdt, states, dtb, A_log, ybuf, pS, pQ);
  ln_reduce<<<kRows / 256, 256, 0, stream>>>(pS, pQ, mu, rstd);
  gemm_bt<float, true><<<dim3(1024 / 128, kRows / 128), 256, 0, stream>>>(
      ybuf, Bt2, out, kRows, 1024, 2048, mu, rstd, t1, t2);
}

// Round 2
// 462.444 us; speedup vs baseline: 1.0208x; 1.0208x over previous
//
#include <hip/hip_runtime.h>
#include <hip/hip_bf16.h>
#include <math.h>

// ---------------------------------------------------------------------------
// Mamba2 forward, MI355X. Round 11: fix the 8-phase in-proj GEMM.
// Round-10 post-mortem: 12 ds_read_b128 per phase (48/K-tile) made the
// kernel LDS-throughput-bound (4608 cyc LDS vs 2048 cyc MFMA per CU-tile)
// -> 140us, MfmaUtil 22.7%. This round: Gray-code phase order
// (A0,B0)->(A0,B1)->(A1,B1)->(A1,B0) with fragment retention in registers,
// so each LDS fragment is read exactly once per K-tile (24 reads: 12/4/8/0
// per phase). Staging schedule, vmcnt gating, barriers, swizzles unchanged.
// Everything else byte-identical to round 10.
// ---------------------------------------------------------------------------

namespace {

constexpr int kB   = 2;
constexpr int kL   = 4096;
constexpr int kDI  = 2048;
constexpr int kDS  = 128;
constexpr int kNH  = 32;
constexpr int kHP  = 64;
constexpr int kDC  = 4;
constexpr int kCS  = 64;
constexpr int kNC  = kL / kCS;
constexpr int kDProj   = 2 * kDI + 2 * kDS + kNH;  // 4384
constexpr int kDProjP  = 4608;                     // 18*256 (8-phase tile pad)
constexpr int kConvDim = kDI + 2 * kDS;            // 2304
constexpr int kRows = kB * kL;                     // 8192
constexpr float kEps = 1e-5f;
constexpr int kTS = 136;   // LDS stride for [64][128] tiles
constexpr int kWS = 72;    // LDS stride for [64][64] tiles

typedef __bf16 bf16x8 __attribute__((ext_vector_type(8)));
typedef float f32x4 __attribute__((ext_vector_type(4)));
typedef unsigned short ushort8 __attribute__((ext_vector_type(8)));

__device__ inline float bu2f(unsigned short u) {
  union { unsigned int i; float f; } x; x.i = ((unsigned int)u) << 16; return x.f;
}
__device__ inline unsigned short f2bu(float f) {
  __hip_bfloat16 h = __float2bfloat16(f);
  return *reinterpret_cast<unsigned short*>(&h);
}

__device__ inline void store_out(float* C, size_t i, float v) { C[i] = v; }
__device__ inline void store_out(unsigned short* C, size_t i, float v) { C[i] = f2bu(v); }

__device__ inline void gld_lds16(const unsigned short* g, unsigned short* l) {
  __builtin_amdgcn_global_load_lds(
      (const __attribute__((address_space(1))) unsigned int*)g,
      (__attribute__((address_space(3))) unsigned int*)l, 16, 0, 0);
}

// ---- C0: cast fp32 -> bf16
__global__ void cast_kernel(const float4* __restrict__ in, ushort4* __restrict__ out, int n4) {
  int i = blockIdx.x * 256 + threadIdx.x;
  if (i >= n4) return;
  float4 v = in[i];
  ushort4 o;
  o.x = f2bu(v.x); o.y = f2bu(v.y); o.z = f2bu(v.z); o.w = f2bu(v.w);
  out[i] = o;
}

// ---- C1/C2: transpose + cast (+optional per-row scale)
__global__ void transpose_cast(const float* __restrict__ in, unsigned short* __restrict__ out,
                               int R, int C, const float* __restrict__ scale) {
  __shared__ float t[32][33];
  const int c0 = blockIdx.x * 32;
  const int r0 = blockIdx.y * 32;
  const int tx = threadIdx.x & 31, ty = threadIdx.x >> 5;
  for (int rr = ty; rr < 32; rr += 8) {
    int c = c0 + tx;
    float v = (c < C) ? in[(size_t)(r0 + rr) * C + c] : 0.f;
    if (scale) v *= scale[r0 + rr];
    t[rr][tx] = v;
  }
  __syncthreads();
  for (int cc = ty; cc < 32; cc += 8) {
    int orow = c0 + cc;
    out[(size_t)orow * R + r0 + tx] = f2bu(t[tx][cc]);
  }
}

// ---- C3: t1[n] = sum_k w[k]*W2[k][n], t2[n] = sum_k b[k]*W2[k][n]
__global__ void colsum_kernel(const float* __restrict__ W2, const float* __restrict__ wv,
                              const float* __restrict__ bv,
                              float* __restrict__ t1, float* __restrict__ t2) {
  __shared__ float p1[4][64], p2[4][64];
  const int nl = threadIdx.x & 63;
  const int ks = threadIdx.x >> 6;
  const int n = blockIdx.x * 64 + nl;
  float s1 = 0.f, s2 = 0.f;
  for (int k = ks * 512; k < ks * 512 + 512; k++) {
    float v = W2[(size_t)k * 1024 + n];
    s1 += wv[k] * v;
    s2 += bv[k] * v;
  }
  p1[ks][nl] = s1; p2[ks][nl] = s2;
  __syncthreads();
  if (threadIdx.x < 64) {
    t1[blockIdx.x * 64 + threadIdx.x] =
        p1[0][threadIdx.x] + p1[1][threadIdx.x] + p1[2][threadIdx.x] + p1[3][threadIdx.x];
    t2[blockIdx.x * 64 + threadIdx.x] =
        p2[0][threadIdx.x] + p2[1][threadIdx.x] + p2[2][threadIdx.x] + p2[3][threadIdx.x];
  }
}

// ---- K1: 256x256 8-phase bf16 GEMM, C[m][n] = sum_k A[m][k]*Bt[n][k].
// 8 waves (2M x 4N), wave tile 128x64, BK=64, double-buffered 128KB LDS.
// Gray-code quadrant order per K-tile: (A0,B0)->(A0,B1)->(A1,B1)->(A1,B0).
// Fragment reads per phase: 12 / 4 / 8 / 0 (each LDS fragment read once per
// K-tile; bf0 retained in registers q0->q3, af reloaded at q2).
// Staging: one dead half-tile per phase; vmcnt(4) only at tile boundaries.
// XOR swizzle slot^=(row&7) on the GLOBAL source (LDS dest linear) and on
// the ds_read address.
#define STG_A(bs, h, t)                                                         \
  gld_lds16(srcA[h][0] + (t) * 64, &sA[bs][(h) * 8192 + wave * 1024]);          \
  gld_lds16(srcA[h][1] + (t) * 64, &sA[bs][(h) * 8192 + wave * 1024 + 512]);
#define STG_B(bs, h, t)                                                         \
  gld_lds16(srcB[h][0] + (t) * 64, &sB[bs][(h) * 8192 + wave * 1024]);          \
  gld_lds16(srcB[h][1] + (t) * 64, &sB[bs][(h) * 8192 + wave * 1024 + 512]);

#define RD_AF(bufA, ha_)                                                        \
  _Pragma("unroll")                                                             \
  for (int i_ = 0; i_ < 4; i_++) {                                              \
    af[i_][0] = *(const bf16x8*)&(bufA)[(ha_) * 8192 + rbaseA + i_ * 1024 + sk0]; \
    af[i_][1] = *(const bf16x8*)&(bufA)[(ha_) * 8192 + rbaseA + i_ * 1024 + sk1]; \
  }
#define RD_BF(bufB, hb_, dst)                                                   \
  _Pragma("unroll")                                                             \
  for (int j_ = 0; j_ < 2; j_++) {                                              \
    dst[j_][0] = *(const bf16x8*)&(bufB)[(hb_) * 8192 + rbaseB + j_ * 1024 + sk0]; \
    dst[j_][1] = *(const bf16x8*)&(bufB)[(hb_) * 8192 + rbaseB + j_ * 1024 + sk1]; \
  }

#define PHW(READS, ha_, hb_, bfr_, STAGE_STMT, TAIL_STMT)                       \
  {                                                                             \
    READS                                                                       \
    STAGE_STMT                                                                  \
    __builtin_amdgcn_s_barrier();                                               \
    asm volatile("s_waitcnt lgkmcnt(0)" ::: "memory");                          \
    __builtin_amdgcn_sched_barrier(0);                                          \
    __builtin_amdgcn_s_setprio(1);                                              \
    _Pragma("unroll")                                                           \
    for (int i_ = 0; i_ < 4; i_++)                                              \
      _Pragma("unroll")                                                         \
      for (int j_ = 0; j_ < 2; j_++) {                                          \
        acc[(ha_) * 4 + i_][(hb_) * 2 + j_] = __builtin_amdgcn_mfma_f32_16x16x32_bf16( \
            af[i_][0], bfr_[j_][0], acc[(ha_) * 4 + i_][(hb_) * 2 + j_], 0, 0, 0); \
        acc[(ha_) * 4 + i_][(hb_) * 2 + j_] = __builtin_amdgcn_mfma_f32_16x16x32_bf16( \
            af[i_][1], bfr_[j_][1], acc[(ha_) * 4 + i_][(hb_) * 2 + j_], 0, 0, 0); \
      }                                                                         \
    __builtin_amdgcn_s_setprio(0);                                              \
    __builtin_amdgcn_sched_barrier(0);                                          \
    TAIL_STMT                                                                   \
    __builtin_amdgcn_s_barrier();                                               \
  }

// One K-tile: Gray-code quadrants with per-phase stage slots S0..S3, tail T3.
#define TILE(cA, cB, S0, S1, S2, S3, T3)                                        \
  PHW(RD_AF(cA, 0) RD_BF(cB, 0, bf0), 0, 0, bf0, S0, {})                        \
  PHW(RD_BF(cB, 1, bf1),              0, 1, bf1, S1, {})                        \
  PHW(RD_AF(cA, 1),                   1, 1, bf1, S2, {})                        \
  PHW({},                             1, 0, bf0, S3, T3)

__global__ __launch_bounds__(512, 2) void gemm_bt_8p(
    const unsigned short* __restrict__ A, const unsigned short* __restrict__ Bt,
    unsigned short* __restrict__ C, int Nreal) {
  constexpr int K = 1024, NT = 16;   // K-tiles of BK=64
  constexpr int GX = kDProjP / 256;  // 18
  constexpr int NWG = GX * (kRows / 256);  // 576, %8 == 0
  __shared__ __align__(16) unsigned short sA[2][16384];
  __shared__ __align__(16) unsigned short sB[2][16384];
  const int tid = (int)threadIdx.x;
  const int wave = tid >> 6, lane = tid & 63;
  const int wm = wave >> 2, wn = wave & 3;
  // T1: bijective XCD swizzle (NWG % 8 == 0)
  const int orig = (int)blockIdx.y * GX + (int)blockIdx.x;
  const int swz = (orig & 7) * (NWG / 8) + (orig >> 3);
  const int m0 = (swz / GX) * 256;
  const int n0 = (swz % GX) * 256;
  // staging source pointers: pre-swizzled global addr, linear LDS dest
  const int l8 = lane >> 3, s8 = lane & 7;
  const unsigned short* srcA[2][2];
  const unsigned short* srcB[2][2];
#pragma unroll
  for (int h = 0; h < 2; h++)
#pragma unroll
    for (int cc = 0; cc < 2; cc++) {
      const int lrow = (wave * 2 + cc) * 8 + l8;       // row within half [0,128)
      const int slot = s8 ^ (lrow & 7);                // inverse of read swizzle
      const int rA = (lrow & 63) + h * 64 + ((lrow >> 6) << 7);
      const int rB = (lrow & 31) + h * 32 + ((lrow >> 5) << 6);
      srcA[h][cc] = A + (size_t)(m0 + rA) * K + slot * 8;
      srcB[h][cc] = Bt + (size_t)(n0 + rB) * K + slot * 8;
    }
  // fragment read offsets (swizzled)
  const int fr = lane & 15, c4 = lane >> 4;
  const int sk0 = (c4 ^ (fr & 7)) * 8;
  const int sk1 = ((4 | c4) ^ (fr & 7)) * 8;
  const int rbaseA = (wm * 64 + fr) * 64;
  const int rbaseB = (wn * 32 + fr) * 64;
  bf16x8 af[4][2], bf0[2][2], bf1[2][2];
  f32x4 acc[8][4] = {};
  unsigned short* const a0 = &sA[0][0];
  unsigned short* const a1 = &sA[1][0];
  unsigned short* const b0 = &sB[0][0];
  unsigned short* const b1 = &sB[1][0];
  // prologue: tile0 complete + tile1 h0 halves; vmcnt(4) leaves tile1-h0 in flight
  STG_A(0, 0, 0) STG_B(0, 0, 0) STG_A(0, 1, 0) STG_B(0, 1, 0)
  STG_A(1, 0, 1) STG_B(1, 0, 1)
  asm volatile("s_waitcnt vmcnt(4)" ::: "memory");
  __builtin_amdgcn_s_barrier();
  for (int u = 0; u < NT; u += 2) {
    const int t1 = u + 1, t2 = u + 2, t3 = u + 3;
    // tile u (even): cur = buf0, next = buf1
    TILE(a0, b0,
         { STG_A(1, 1, t1) },
         { STG_B(1, 1, t1) },
         { if (t2 < NT) { STG_A(0, 0, t2) } },
         { if (t2 < NT) { STG_B(0, 0, t2) } },
         { if (t2 < NT) { asm volatile("s_waitcnt vmcnt(4)" ::: "memory"); }
           else { asm volatile("s_waitcnt vmcnt(0)" ::: "memory"); } })
    // tile u+1 (odd): cur = buf1, next = buf0
    TILE(a1, b1,
         { if (t2 < NT) { STG_A(0, 1, t2) } },
         { if (t2 < NT) { STG_B(0, 1, t2) } },
         { if (t3 < NT) { STG_A(1, 0, t3) } },
         { if (t3 < NT) { STG_B(1, 0, t3) } },
         { if (t3 < NT) { asm volatile("s_waitcnt vmcnt(4)" ::: "memory"); }
           else { asm volatile("s_waitcnt vmcnt(0)" ::: "memory"); } })
  }
  // epilogue: acc[ii][jj] -> m offset (ii>>2)*64 + (ii&3)*16, n offset (jj>>1)*32 + (jj&1)*16
  const int crow = c4 * 4;
#pragma unroll
  for (int ii = 0; ii < 8; ii++) {
    const int mbase = m0 + wm * 128 + (ii >> 2) * 64 + (ii & 3) * 16 + crow;
#pragma unroll
    for (int jj = 0; jj < 4; jj++) {
      const int n = n0 + wn * 64 + (jj >> 1) * 32 + (jj & 1) * 16 + fr;
      if (n < Nreal) {
#pragma unroll
        for (int r = 0; r < 4; r++)
          C[(size_t)(mbase + r) * Nreal + n] = f2bu(acc[ii][jj][r]);
      }
    }
  }
}
#undef TILE
#undef PHW
#undef RD_AF
#undef RD_BF
#undef STG_A
#undef STG_B

// ---- old MFMA GEMM with XOR-swizzled LDS (kept for the FOLD output GEMM).
template <typename OutT, bool FOLD>
__global__ __launch_bounds__(256) void gemm_bt(const unsigned short* __restrict__ A,
                                               const unsigned short* __restrict__ Bt,
                                               OutT* __restrict__ C, int M, int N, int K,
                                               const float* __restrict__ mu,
                                               const float* __restrict__ rstd,
                                               const float* __restrict__ t1,
                                               const float* __restrict__ t2) {
  __shared__ __align__(16) unsigned short As[128 * 32];
  __shared__ __align__(16) unsigned short Bs[128 * 32];
  const int tid = threadIdx.x;
  const int wave = tid >> 6, lane = tid & 63;
  const int m0 = blockIdx.y * 128, n0 = blockIdx.x * 128;
  const int wr = (wave >> 1) * 64, wc = (wave & 1) * 64;
  const int st_row = lane >> 2;
  const int st_col = (((lane & 3) ^ ((st_row >> 1) & 3))) * 8;  // XOR swizzle
  const unsigned short* pA[2];
  const unsigned short* pB[2];
  unsigned short* lA[2];
  unsigned short* lB[2];
#pragma unroll
  for (int r = 0; r < 2; r++) {
    int q = wave * 2 + r;
    pA[r] = A + (size_t)(m0 + q * 16 + st_row) * K + st_col;
    pB[r] = Bt + (size_t)(n0 + q * 16 + st_row) * K + st_col;
    lA[r] = &As[q * 512];
    lB[r] = &Bs[q * 512];
  }
  const int frag_row = lane & 15;
  const int rk = (((lane >> 4) ^ ((frag_row >> 1) & 3))) * 8;
  f32x4 acc[4][4] = {};
  for (int k0 = 0; k0 < K; k0 += 32) {
#pragma unroll
    for (int r = 0; r < 2; r++) {
      gld_lds16(pA[r] + k0, lA[r]);
      gld_lds16(pB[r] + k0, lB[r]);
    }
    asm volatile("s_waitcnt vmcnt(0)" ::: "memory");
    __syncthreads();
    bf16x8 af[4], bfr[4];
#pragma unroll
    for (int i = 0; i < 4; i++)
      af[i] = *(const bf16x8*)&As[(wr + i * 16 + frag_row) * 32 + rk];
#pragma unroll
    for (int j = 0; j < 4; j++)
      bfr[j] = *(const bf16x8*)&Bs[(wc + j * 16 + frag_row) * 32 + rk];
#pragma unroll
    for (int i = 0; i < 4; i++)
#pragma unroll
      for (int j = 0; j < 4; j++)
        acc[i][j] = __builtin_amdgcn_mfma_f32_16x16x32_bf16(af[i], bfr[j], acc[i][j], 0, 0, 0);
    __syncthreads();
  }
  const int crow = (lane >> 4) * 4;
  const int ccol = lane & 15;
#pragma unroll
  for (int i = 0; i < 4; i++) {
#pragma unroll
    for (int j = 0; j < 4; j++) {
      int n = n0 + wc + j * 16 + ccol;
      if (n < N) {
        float c1 = FOLD ? t1[n] : 0.f;
        float c2 = FOLD ? t2[n] : 0.f;
#pragma unroll
        for (int r = 0; r < 4; r++) {
          int m = m0 + wr + i * 16 + crow + r;
          float v = acc[i][j][r];
          if (FOLD) v = rstd[m] * (v - mu[m] * c1) + c2;
          store_out(C, (size_t)m * N + n, v);
        }
      }
    }
  }
}

// ---- K2: dt = softplus(dt_raw + dt_bias)
__global__ void dt_kernel(const unsigned short* __restrict__ zxbcdt,
                          const float* __restrict__ dt_bias,
                          float* __restrict__ dtbuf) {
  int idx = blockIdx.x * 256 + threadIdx.x;
  if (idx >= kRows * kNH) return;
  int row = idx >> 5, h = idx & 31;
  float x = bu2f(zxbcdt[(size_t)row * kDProj + (kDProj - kNH) + h]) + dt_bias[h];
  dtbuf[idx] = (x > 15.f) ? x : log1pf(expf(x));
}

// ---- K3: causal depthwise conv (k=4) + SiLU, 8 rows x 4 cols per thread
__global__ void conv_silu_kernel(const unsigned short* __restrict__ zxbcdt,
                                 const float* __restrict__ conv_w,
                                 const float* __restrict__ conv_b,
                                 unsigned short* __restrict__ xbc_act) {
  int c4 = blockIdx.x * 256 + threadIdx.x;
  if (c4 >= kConvDim / 4) return;
  const int c = c4 * 4;
  const int r0 = blockIdx.y * 8;
  const int l0 = r0 & (kL - 1);
  float4 w[4];
  float bias[4];
#pragma unroll
  for (int q = 0; q < 4; q++) {
    w[q] = ((const float4*)conv_w)[c + q];
    bias[q] = conv_b[c + q];
  }
  float v[11][4];
#pragma unroll
  for (int i = 0; i < 11; i++) {
    int l = l0 - 3 + i;
    if (l >= 0) {
      ushort4 t = *(const ushort4*)&zxbcdt[(size_t)(r0 - 3 + i) * kDProj + kDI + c];
      v[i][0] = bu2f(t.x); v[i][1] = bu2f(t.y); v[i][2] = bu2f(t.z); v[i][3] = bu2f(t.w);
    } else {
      v[i][0] = v[i][1] = v[i][2] = v[i][3] = 0.f;
    }
  }
#pragma unroll
  for (int j = 0; j < 8; j++) {
    ushort4 o;
    unsigned short* op = (unsigned short*)&o;
#pragma unroll
    for (int q = 0; q < 4; q++) {
      float a = bias[q] + v[j][q] * w[q].x + v[j + 1][q] * w[q].y +
                v[j + 2][q] * w[q].z + v[j + 3][q] * w[q].w;
      op[q] = f2bu(a / (1.f + expf(-a)));
    }
    *(ushort4*)&xbc_act[(size_t)(r0 + j) * kConvDim + c] = o;
  }
}

// ---- K4: per-(b,chunk,head) end-of-chunk state via MFMA
__global__ __launch_bounds__(256) void chunk_state_kernel(
    const unsigned short* __restrict__ xbc_act,
    const float* __restrict__ dtbuf,
    const float* __restrict__ A_log,
    unsigned short* __restrict__ states,
    float* __restrict__ asum) {
  const int id = blockIdx.x;
  const int h = id & 31;
  const int c = (id >> 5) & (kNC - 1);
  const int b = id >> 11;
  const int tid = threadIdx.x;
  const int wave = tid >> 6, lane = tid & 63;
  __shared__ __align__(16) unsigned short sBT[kDS * kWS];
  __shared__ __align__(16) unsigned short sxd[kCS * kWS];
  __shared__ float s_dt[kCS];
  __shared__ float s_acum[kCS];
  const int l0 = b * kL + c * kCS;
  if (tid < kCS) s_dt[tid] = dtbuf[(size_t)(l0 + tid) * kNH + h];
  __syncthreads();
  if (tid == 0) {
    float A = -expf(A_log[h]);
    float run = 0.f;
    for (int s = 0; s < kCS; s++) { run += A * s_dt[s]; s_acum[s] = run; }
    asum[id] = run;
  }
  __syncthreads();
  const float total = s_acum[kCS - 1];
  for (int e = tid; e < kCS * kDS; e += 256) {
    int s = e >> 7, n = e & 127;
    sBT[n * kWS + s] = xbc_act[(size_t)(l0 + s) * kConvDim + kDI + n];
  }
  for (int e = tid; e < kCS * kHP; e += 256) {
    int s = e >> 6, p = e & 63;
    float xv = bu2f(xbc_act[(size_t)(l0 + s) * kConvDim + h * kHP + p]);
    sxd[p * kWS + s] = f2bu(xv * s_dt[s] * expf(total - s_acum[s]));
  }
  __syncthreads();
  const int arow = wave * 16 + (lane & 15);
  const int fk = (lane >> 4) * 8;
  f32x4 acc[8] = {};
#pragma unroll
  for (int kk = 0; kk < 2; kk++) {
    bf16x8 a = *(const bf16x8*)&sxd[arow * kWS + kk * 32 + fk];
#pragma unroll
    for (int j = 0; j < 8; j++) {
      bf16x8 bb = *(const bf16x8*)&sBT[(j * 16 + (lane & 15)) * kWS + kk * 32 + fk];
      acc[j] = __builtin_amdgcn_mfma_f32_16x16x32_bf16(a, bb, acc[j], 0, 0, 0);
    }
  }
  const int prow = wave * 16 + (lane >> 4) * 4;
  const int ncol = lane & 15;
  size_t base = (size_t)id * (kHP * kDS);
#pragma unroll
  for (int j = 0; j < 8; j++)
#pragma unroll
    for (int r = 0; r < 4; r++)
      states[base + (size_t)(prow + r) * kDS + j * 16 + ncol] = f2bu(acc[j][r]);
}

// ---- K5: sequential inter-chunk scan with software prefetch
__global__ void scan_kernel(unsigned short* __restrict__ states,
                            const float* __restrict__ asum) {
  const int blk = blockIdx.x;
  const int seg = blk & 7;
  const int bh = blk >> 3;
  const int h = bh & 31, b = bh >> 5;
  const int e4 = seg * 256 + threadIdx.x;
  const size_t cstride = (size_t)kNH * 2048;            // ushort4 units per chunk
  ushort4* p = (ushort4*)states + ((size_t)(b * kNC) * kNH + h) * 2048 + e4;
  const float* ap = asum + (b * kNC) * kNH + h;
  float c0 = 0.f, c1 = 0.f, c2 = 0.f, c3 = 0.f;
  ushort4 t = p[0];
  float dec = expf(ap[0]);
  for (int c = 0; c < kNC; c++) {
    ushort4 tn = t;
    float decn = dec;
    if (c + 1 < kNC) {                                  // prefetch next chunk
      tn = p[(size_t)(c + 1) * cstride];
      decn = expf(ap[(c + 1) * kNH]);
    }
    ushort4 o;
    o.x = f2bu(c0); o.y = f2bu(c1); o.z = f2bu(c2); o.w = f2bu(c3);
    p[(size_t)c * cstride] = o;
    c0 = c0 * dec + bu2f(t.x);
    c1 = c1 * dec + bu2f(t.y);
    c2 = c2 * dec + bu2f(t.z);
    c3 = c3 * dec + bu2f(t.w);
    t = tn; dec = decn;
  }
}

// ---- K6: intra-chunk Y, 4 heads/block (round-6 version: Sin staged via LDS)
__global__ __launch_bounds__(256) void y_kernel(
    const unsigned short* __restrict__ xbc_act,
    const unsigned short* __restrict__ zxbcdt,
    const unsigned short* __restrict__ states_in,
    const float* __restrict__ dtbuf,
    const float* __restrict__ A_log,
    unsigned short* __restrict__ ybuf,
    float* __restrict__ pS, float* __restrict__ pQ) {
  const int id = blockIdx.x;                 // (b*NC + c)*8 + hg
  const int hg = id & 7;
  const int c = (id >> 3) & (kNC - 1);
  const int b = id >> 9;
  const int tid = threadIdx.x;
  const int wave = tid >> 6, lane = tid & 63;
  __shared__ __align__(16) unsigned short sC[kCS * kTS];
  __shared__ __align__(16) unsigned short sB[kCS * kTS];
  __shared__ __align__(16) unsigned short sxd[kCS * kWS];
  __shared__ __align__(16) unsigned short sW[kCS * kWS];
  __shared__ float s_dt[4][kCS];
  __shared__ float s_acum[4][kCS];
  const int l0 = b * kL + c * kCS;
  {
    int hh = tid >> 6, s = tid & 63;
    s_dt[hh][s] = dtbuf[(size_t)(l0 + s) * kNH + hg * 4 + hh];
  }
  __syncthreads();
  if (tid < 4) {
    float A = -expf(A_log[hg * 4 + tid]);
    float run = 0.f;
    for (int s = 0; s < kCS; s++) { run += A * s_dt[tid][s]; s_acum[tid][s] = run; }
  }
  for (int e = tid; e < kCS * 16; e += 256) {
    int row = e >> 4, c8 = (e & 15) * 8;
    size_t rb = (size_t)(l0 + row) * kConvDim;
    *(ushort8*)&sB[row * kTS + c8] = *(const ushort8*)&xbc_act[rb + kDI + c8];
    *(ushort8*)&sC[row * kTS + c8] = *(const ushort8*)&xbc_act[rb + kDI + kDS + c8];
  }
  __syncthreads();
  const int arow = wave * 16 + (lane & 15);
  const int fk = (lane >> 4) * 8;
  // G[l][s] = C . B^T  (K=128) — head-independent, once per block
  f32x4 accG[4] = {};
#pragma unroll
  for (int kk = 0; kk < 4; kk++) {
    bf16x8 a = *(const bf16x8*)&sC[arow * kTS + kk * 32 + fk];
#pragma unroll
    for (int j = 0; j < 4; j++) {
      bf16x8 bb = *(const bf16x8*)&sB[(j * 16 + (lane & 15)) * kTS + kk * 32 + fk];
      accG[j] = __builtin_amdgcn_mfma_f32_16x16x32_bf16(a, bb, accG[j], 0, 0, 0);
    }
  }
  const int lrow = wave * 16 + (lane >> 4) * 4;
  const size_t sbase = (size_t)((b * kNC + c) * kNH) * (kHP * kDS);
  float rS[4] = {}, rQ[4] = {};
  for (int hh = 0; hh < 4; hh++) {
    const int h = hg * 4 + hh;
    __syncthreads();   // prior iteration (or G) done reading sB/sxd/sW
    // stage xd^T for this head
    for (int e = tid; e < kCS * kHP; e += 256) {
      int s = e >> 6, p = e & 63;
      float xv = bu2f(xbc_act[(size_t)(l0 + s) * kConvDim + h * kHP + p]);
      sxd[p * kWS + s] = f2bu(xv * s_dt[hh][s]);
    }
    // W = mask(G)*decay  (wave-local strip)
#pragma unroll
    for (int j = 0; j < 4; j++) {
      int scol = j * 16 + (lane & 15);
      float as = s_acum[hh][scol];
#pragma unroll
      for (int r = 0; r < 4; r++) {
        int l = lrow + r;
        float w = (scol <= l) ? accG[j][r] * expf(s_acum[hh][l] - as) : 0.f;
        sW[l * kWS + scol] = f2bu(w);
      }
    }
    // stage Sin[p][n] for this head into sB
    for (int e = tid; e < kCS * 16; e += 256) {
      int row = e >> 4, c8 = (e & 15) * 8;
      *(ushort8*)&sB[row * kTS + c8] =
          *(const ushort8*)&states_in[sbase + (size_t)h * (kHP * kDS) + row * kDS + c8];
    }
    __syncthreads();
    // Yd = W . xd^T  (K=64)
    f32x4 accY[4] = {};
#pragma unroll
    for (int kk = 0; kk < 2; kk++) {
      bf16x8 a = *(const bf16x8*)&sW[arow * kWS + kk * 32 + fk];
#pragma unroll
      for (int j = 0; j < 4; j++) {
        bf16x8 bb = *(const bf16x8*)&sxd[(j * 16 + (lane & 15)) * kWS + kk * 32 + fk];
        accY[j] = __builtin_amdgcn_mfma_f32_16x16x32_bf16(a, bb, accY[j], 0, 0, 0);
      }
    }
    // Yoff = C . Sin^T  (K=128)
    f32x4 accO[4] = {};
#pragma unroll
    for (int kk = 0; kk < 4; kk++) {
      bf16x8 a = *(const bf16x8*)&sC[arow * kTS + kk * 32 + fk];
#pragma unroll
      for (int j = 0; j < 4; j++) {
        bf16x8 bb = *(const bf16x8*)&sB[(j * 16 + (lane & 15)) * kTS + kk * 32 + fk];
        accO[j] = __builtin_amdgcn_mfma_f32_16x16x32_bf16(a, bb, accO[j], 0, 0, 0);
      }
    }
#pragma unroll
    for (int r = 0; r < 4; r++) {
      int l = lrow + r;
      float el = expf(s_acum[hh][l]);
      size_t zrow = (size_t)(l0 + l) * kDProj + h * kHP;
      size_t yrow = (size_t)(l0 + l) * kDI + h * kHP;
#pragma unroll
      for (int j = 0; j < 4; j++) {
        int p = j * 16 + (lane & 15);
        float yv = accY[j][r] + el * accO[j][r];
        float z = bu2f(zxbcdt[zrow + p]);
        yv *= z / (1.f + expf(-z));
        rS[r] += yv;
        rQ[r] += yv * yv;
        ybuf[yrow + p] = f2bu(yv);
      }
    }
  }
#pragma unroll
  for (int m = 1; m < 16; m <<= 1) {
#pragma unroll
    for (int r = 0; r < 4; r++) {
      rS[r] += __shfl_xor(rS[r], m);
      rQ[r] += __shfl_xor(rQ[r], m);
    }
  }
  if ((lane & 15) == 0) {
#pragma unroll
    for (int r = 0; r < 4; r++) {
      int row = l0 + lrow + r;
      pS[(size_t)row * 8 + hg] = rS[r];
      pQ[(size_t)row * 8 + hg] = rQ[r];
    }
  }
}

// ---- K7: finalize LN stats from per-block partials
__global__ void ln_reduce(const float* __restrict__ pS, const float* __restrict__ pQ,
                          float* __restrict__ mu, float* __restrict__ rstd) {
  int row = blockIdx.x * 256 + threadIdx.x;
  if (row >= kRows) return;
  float s = 0.f, q = 0.f;
#pragma unroll
  for (int i = 0; i < 8; i++) { s += pS[(size_t)row * 8 + i]; q += pQ[(size_t)row * 8 + i]; }
  float m = s / kDI;
  mu[row] = m;
  rstd[row] = rsqrtf(q / kDI - m * m + kEps);
}

}  // namespace

extern "C" void kernel_launch(void* const* d_in, const int* in_sizes, int n_in,
                              void* d_out, int out_size, void* d_ws, size_t ws_size,
                              hipStream_t stream) {
  const float* u       = (const float*)d_in[0];
  const float* W_in    = (const float*)d_in[1];
  const float* conv_w  = (const float*)d_in[2];
  const float* conv_b  = (const float*)d_in[3];
  const float* dt_bias = (const float*)d_in[4];
  const float* A_log   = (const float*)d_in[5];
  const float* norm_w  = (const float*)d_in[6];
  const float* norm_b  = (const float*)d_in[7];
  const float* W_out   = (const float*)d_in[8];
  float* out = (float*)d_out;

  char* ws = (char*)d_ws;
  size_t off = 0;
  auto alloc = [&](size_t bytes) {
    void* p = ws + off;
    off += (bytes + 255) & ~(size_t)255;
    return p;
  };
  unsigned short* zxbcdt = (unsigned short*)alloc((size_t)kRows * kDProj * 2);        // 71.8 MB
  unsigned short* xbc    = (unsigned short*)alloc((size_t)kRows * kConvDim * 2);      // 37.7 MB
  float* dtb             = (float*)alloc((size_t)kRows * kNH * 4);                    //  1.0 MB
  float* asum            = (float*)alloc((size_t)kB * kNC * kNH * 4);                 // 16 KB
  unsigned short* A1     = (unsigned short*)alloc((size_t)kRows * 1024 * 2);          // 16.8 MB
  unsigned short* Bt1    = (unsigned short*)alloc((size_t)kDProjP * 1024 * 2);        //  9.4 MB
  unsigned short* states = (unsigned short*)alloc((size_t)kB * kNC * kNH * kHP * kDS * 2); // 67.1 MB
  unsigned short* Bt2    = (unsigned short*)alloc((size_t)1024 * kDI * 2);            //  4.2 MB
  unsigned short* ybuf   = (unsigned short*)alloc((size_t)kRows * kDI * 2);           // 33.6 MB
  float* mu              = (float*)alloc((size_t)kRows * 4);
  float* rstd            = (float*)alloc((size_t)kRows * 4);
  float* t1              = (float*)alloc(1024 * 4);
  float* t2              = (float*)alloc(1024 * 4);
  float* pS              = (float*)alloc((size_t)kRows * 8 * 4);                      // 256 KB
  float* pQ              = (float*)alloc((size_t)kRows * 8 * 4);                      // 256 KB
  (void)ws_size; (void)in_sizes; (void)n_in; (void)out_size;

  cast_kernel<<<(kRows * 1024 / 4 + 255) / 256, 256, 0, stream>>>(
      (const float4*)u, (ushort4*)A1, kRows * 1024 / 4);
  transpose_cast<<<dim3(kDProjP / 32, 1024 / 32), 256, 0, stream>>>(
      W_in, Bt1, 1024, kDProj, nullptr);
  transpose_cast<<<dim3(1024 / 32, 2048 / 32), 256, 0, stream>>>(
      W_out, Bt2, 2048, 1024, norm_w);
  colsum_kernel<<<16, 256, 0, stream>>>(W_out, norm_w, norm_b, t1, t2);
  gemm_bt_8p<<<dim3(kDProjP / 256, kRows / 256), 512, 0, stream>>>(
      A1, Bt1, zxbcdt, kDProj);
  dt_kernel<<<(kRows * kNH + 255) / 256, 256, 0, stream>>>(zxbcdt, dt_bias, dtb);
  conv_silu_kernel<<<dim3(3, kRows / 8), 256, 0, stream>>>(zxbcdt, conv_w, conv_b, xbc);
  chunk_state_kernel<<<kB * kNC * kNH, 256, 0, stream>>>(xbc, dtb, A_log, states, asum);
  scan_kernel<<<kB * kNH * 8, 256, 0, stream>>>(states, asum);
  y_kernel<<<kB * kNC * 8, 256, 0, stream>>>(xbc, zxbcdt, states, dtb, A_log, ybuf, pS, pQ);
  ln_reduce<<<kRows / 256, 256, 0, stream>>>(pS, pQ, mu, rstd);
  gemm_bt<float, true><<<dim3(1024 / 128, kRows / 128), 256, 0, stream>>>(
      ybuf, Bt2, out, kRows, 1024, 2048, mu, rstd, t1, t2);
}

// Round 3
// 437.639 us; speedup vs baseline: 1.0787x; 1.0567x over previous
//
#include <hip/hip_runtime.h>
#include <hip/hip_bf16.h>
#include <math.h>

// ---------------------------------------------------------------------------
// Mamba2 forward, MI355X. Round 12: abandon the 8-phase 256^2 port (two
// rounds, never beat 116.6us). Back to the round-9 128^2 structure with two
// mechanism-backed upgrades to gemm_bt (used by BOTH big GEMMs):
//   - BK=64: halves barrier+vmcnt(0)-drain events per unit K work
//     (32KB LDS, still 3 blocks/CU; slot-XOR swizzle extended to 8 slots).
//   - T1 bijective XCD blockIdx swizzle (grids 2240 and 512, both %8==0).
// Everything else byte-identical to round 9:
//   C0 cast, C1/C2 transpose, C3 colsum, K2 dt, K3 conv_silu, K4 chunk_state,
//   K5 scan, K6 y, K7 ln_reduce.
// ---------------------------------------------------------------------------

namespace {

constexpr int kB   = 2;
constexpr int kL   = 4096;
constexpr int kDI  = 2048;
constexpr int kDS  = 128;
constexpr int kNH  = 32;
constexpr int kHP  = 64;
constexpr int kDC  = 4;
constexpr int kCS  = 64;
constexpr int kNC  = kL / kCS;
constexpr int kDProj   = 2 * kDI + 2 * kDS + kNH;  // 4384
constexpr int kDProjP  = 4480;                     // 35*128
constexpr int kConvDim = kDI + 2 * kDS;            // 2304
constexpr int kRows = kB * kL;                     // 8192
constexpr float kEps = 1e-5f;
constexpr int kTS = 136;   // LDS stride for [64][128] tiles
constexpr int kWS = 72;    // LDS stride for [64][64] tiles

typedef __bf16 bf16x8 __attribute__((ext_vector_type(8)));
typedef float f32x4 __attribute__((ext_vector_type(4)));
typedef unsigned short ushort8 __attribute__((ext_vector_type(8)));

__device__ inline float bu2f(unsigned short u) {
  union { unsigned int i; float f; } x; x.i = ((unsigned int)u) << 16; return x.f;
}
__device__ inline unsigned short f2bu(float f) {
  __hip_bfloat16 h = __float2bfloat16(f);
  return *reinterpret_cast<unsigned short*>(&h);
}

__device__ inline void store_out(float* C, size_t i, float v) { C[i] = v; }
__device__ inline void store_out(unsigned short* C, size_t i, float v) { C[i] = f2bu(v); }

__device__ inline void gld_lds16(const unsigned short* g, unsigned short* l) {
  __builtin_amdgcn_global_load_lds(
      (const __attribute__((address_space(1))) unsigned int*)g,
      (__attribute__((address_space(3))) unsigned int*)l, 16, 0, 0);
}

// ---- C0: cast fp32 -> bf16
__global__ void cast_kernel(const float4* __restrict__ in, ushort4* __restrict__ out, int n4) {
  int i = blockIdx.x * 256 + threadIdx.x;
  if (i >= n4) return;
  float4 v = in[i];
  ushort4 o;
  o.x = f2bu(v.x); o.y = f2bu(v.y); o.z = f2bu(v.z); o.w = f2bu(v.w);
  out[i] = o;
}

// ---- C1/C2: transpose + cast (+optional per-row scale)
__global__ void transpose_cast(const float* __restrict__ in, unsigned short* __restrict__ out,
                               int R, int C, const float* __restrict__ scale) {
  __shared__ float t[32][33];
  const int c0 = blockIdx.x * 32;
  const int r0 = blockIdx.y * 32;
  const int tx = threadIdx.x & 31, ty = threadIdx.x >> 5;
  for (int rr = ty; rr < 32; rr += 8) {
    int c = c0 + tx;
    float v = (c < C) ? in[(size_t)(r0 + rr) * C + c] : 0.f;
    if (scale) v *= scale[r0 + rr];
    t[rr][tx] = v;
  }
  __syncthreads();
  for (int cc = ty; cc < 32; cc += 8) {
    int orow = c0 + cc;
    out[(size_t)orow * R + r0 + tx] = f2bu(t[tx][cc]);
  }
}

// ---- C3: t1[n] = sum_k w[k]*W2[k][n], t2[n] = sum_k b[k]*W2[k][n]
__global__ void colsum_kernel(const float* __restrict__ W2, const float* __restrict__ wv,
                              const float* __restrict__ bv,
                              float* __restrict__ t1, float* __restrict__ t2) {
  __shared__ float p1[4][64], p2[4][64];
  const int nl = threadIdx.x & 63;
  const int ks = threadIdx.x >> 6;
  const int n = blockIdx.x * 64 + nl;
  float s1 = 0.f, s2 = 0.f;
  for (int k = ks * 512; k < ks * 512 + 512; k++) {
    float v = W2[(size_t)k * 1024 + n];
    s1 += wv[k] * v;
    s2 += bv[k] * v;
  }
  p1[ks][nl] = s1; p2[ks][nl] = s2;
  __syncthreads();
  if (threadIdx.x < 64) {
    t1[blockIdx.x * 64 + threadIdx.x] =
        p1[0][threadIdx.x] + p1[1][threadIdx.x] + p1[2][threadIdx.x] + p1[3][threadIdx.x];
    t2[blockIdx.x * 64 + threadIdx.x] =
        p2[0][threadIdx.x] + p2[1][threadIdx.x] + p2[2][threadIdx.x] + p2[3][threadIdx.x];
  }
}

// ---- MFMA GEMM, 128x128 tile, BK=64, XOR-swizzled LDS, XCD-swizzled grid.
// FOLD applies LayerNorm in epilogue.
template <typename OutT, bool FOLD>
__global__ __launch_bounds__(256, 3) void gemm_bt(const unsigned short* __restrict__ A,
                                                  const unsigned short* __restrict__ Bt,
                                                  OutT* __restrict__ C, int M, int N, int K,
                                                  const float* __restrict__ mu,
                                                  const float* __restrict__ rstd,
                                                  const float* __restrict__ t1,
                                                  const float* __restrict__ t2) {
  __shared__ __align__(16) unsigned short As[128 * 64];   // 16 KB
  __shared__ __align__(16) unsigned short Bs[128 * 64];   // 16 KB
  const int tid = threadIdx.x;
  const int wave = tid >> 6, lane = tid & 63;
  // T1: bijective XCD swizzle (both grids are multiples of 8)
  const int nwg = (int)(gridDim.x * gridDim.y);
  const int orig = (int)(blockIdx.y * gridDim.x + blockIdx.x);
  const int swz = (orig & 7) * (nwg >> 3) + (orig >> 3);
  const int bx = swz % (int)gridDim.x, by = swz / (int)gridDim.x;
  const int m0 = by * 128, n0 = bx * 128;
  const int wr = (wave >> 1) * 64, wc = (wave & 1) * 64;
  // staging: 4 segments per matrix per thread; lane covers row l8, slot s8.
  // LDS[row][s] holds global[row][s ^ (row&7)]  (write: dest linear, source
  // pre-swizzled; read: slot ^ (row&7)). Conflict-free by quarter-wave phasing.
  const int l8 = lane >> 3, s8 = lane & 7;
  const unsigned short* pA[4];
  const unsigned short* pB[4];
  unsigned short* lA[4];
  unsigned short* lB[4];
#pragma unroll
  for (int r = 0; r < 4; r++) {
    int q = wave * 4 + r;                       // 16 segments x 8 rows = 128 rows
    pA[r] = A + (size_t)(m0 + q * 8 + l8) * K + (s8 ^ l8) * 8;
    pB[r] = Bt + (size_t)(n0 + q * 8 + l8) * K + (s8 ^ l8) * 8;
    lA[r] = &As[q * 512];
    lB[r] = &Bs[q * 512];
  }
  const int fr = lane & 15;
  const int c4 = lane >> 4;
  const int sk0 = (c4 ^ (fr & 7)) * 8;          // kk=0: slots 0..3, swizzled
  const int sk1 = ((4 | c4) ^ (fr & 7)) * 8;    // kk=1: slots 4..7, swizzled
  f32x4 acc[4][4] = {};
  for (int k0 = 0; k0 < K; k0 += 64) {
#pragma unroll
    for (int r = 0; r < 4; r++) {
      gld_lds16(pA[r] + k0, lA[r]);
      gld_lds16(pB[r] + k0, lB[r]);
    }
    asm volatile("s_waitcnt vmcnt(0)" ::: "memory");
    __syncthreads();
    {
      bf16x8 af0[4], bf0[4];
#pragma unroll
      for (int i = 0; i < 4; i++) {
        af0[i] = *(const bf16x8*)&As[(wr + i * 16 + fr) * 64 + sk0];
        bf0[i] = *(const bf16x8*)&Bs[(wc + i * 16 + fr) * 64 + sk0];
      }
#pragma unroll
      for (int i = 0; i < 4; i++)
#pragma unroll
        for (int j = 0; j < 4; j++)
          acc[i][j] = __builtin_amdgcn_mfma_f32_16x16x32_bf16(af0[i], bf0[j], acc[i][j], 0, 0, 0);
    }
    {
      bf16x8 af1[4], bf1[4];
#pragma unroll
      for (int i = 0; i < 4; i++) {
        af1[i] = *(const bf16x8*)&As[(wr + i * 16 + fr) * 64 + sk1];
        bf1[i] = *(const bf16x8*)&Bs[(wc + i * 16 + fr) * 64 + sk1];
      }
#pragma unroll
      for (int i = 0; i < 4; i++)
#pragma unroll
        for (int j = 0; j < 4; j++)
          acc[i][j] = __builtin_amdgcn_mfma_f32_16x16x32_bf16(af1[i], bf1[j], acc[i][j], 0, 0, 0);
    }
    __syncthreads();
  }
  const int crow = (lane >> 4) * 4;
  const int ccol = lane & 15;
#pragma unroll
  for (int i = 0; i < 4; i++) {
#pragma unroll
    for (int j = 0; j < 4; j++) {
      int n = n0 + wc + j * 16 + ccol;
      if (n < N) {
        float c1 = FOLD ? t1[n] : 0.f;
        float c2 = FOLD ? t2[n] : 0.f;
#pragma unroll
        for (int r = 0; r < 4; r++) {
          int m = m0 + wr + i * 16 + crow + r;
          float v = acc[i][j][r];
          if (FOLD) v = rstd[m] * (v - mu[m] * c1) + c2;
          store_out(C, (size_t)m * N + n, v);
        }
      }
    }
  }
}

// ---- K2: dt = softplus(dt_raw + dt_bias)
__global__ void dt_kernel(const unsigned short* __restrict__ zxbcdt,
                          const float* __restrict__ dt_bias,
                          float* __restrict__ dtbuf) {
  int idx = blockIdx.x * 256 + threadIdx.x;
  if (idx >= kRows * kNH) return;
  int row = idx >> 5, h = idx & 31;
  float x = bu2f(zxbcdt[(size_t)row * kDProj + (kDProj - kNH) + h]) + dt_bias[h];
  dtbuf[idx] = (x > 15.f) ? x : log1pf(expf(x));
}

// ---- K3: causal depthwise conv (k=4) + SiLU, 8 rows x 4 cols per thread
__global__ void conv_silu_kernel(const unsigned short* __restrict__ zxbcdt,
                                 const float* __restrict__ conv_w,
                                 const float* __restrict__ conv_b,
                                 unsigned short* __restrict__ xbc_act) {
  int c4 = blockIdx.x * 256 + threadIdx.x;
  if (c4 >= kConvDim / 4) return;
  const int c = c4 * 4;
  const int r0 = blockIdx.y * 8;
  const int l0 = r0 & (kL - 1);
  float4 w[4];
  float bias[4];
#pragma unroll
  for (int q = 0; q < 4; q++) {
    w[q] = ((const float4*)conv_w)[c + q];
    bias[q] = conv_b[c + q];
  }
  float v[11][4];
#pragma unroll
  for (int i = 0; i < 11; i++) {
    int l = l0 - 3 + i;
    if (l >= 0) {
      ushort4 t = *(const ushort4*)&zxbcdt[(size_t)(r0 - 3 + i) * kDProj + kDI + c];
      v[i][0] = bu2f(t.x); v[i][1] = bu2f(t.y); v[i][2] = bu2f(t.z); v[i][3] = bu2f(t.w);
    } else {
      v[i][0] = v[i][1] = v[i][2] = v[i][3] = 0.f;
    }
  }
#pragma unroll
  for (int j = 0; j < 8; j++) {
    ushort4 o;
    unsigned short* op = (unsigned short*)&o;
#pragma unroll
    for (int q = 0; q < 4; q++) {
      float a = bias[q] + v[j][q] * w[q].x + v[j + 1][q] * w[q].y +
                v[j + 2][q] * w[q].z + v[j + 3][q] * w[q].w;
      op[q] = f2bu(a / (1.f + expf(-a)));
    }
    *(ushort4*)&xbc_act[(size_t)(r0 + j) * kConvDim + c] = o;
  }
}

// ---- K4: per-(b,chunk,head) end-of-chunk state via MFMA
__global__ __launch_bounds__(256) void chunk_state_kernel(
    const unsigned short* __restrict__ xbc_act,
    const float* __restrict__ dtbuf,
    const float* __restrict__ A_log,
    unsigned short* __restrict__ states,
    float* __restrict__ asum) {
  const int id = blockIdx.x;
  const int h = id & 31;
  const int c = (id >> 5) & (kNC - 1);
  const int b = id >> 11;
  const int tid = threadIdx.x;
  const int wave = tid >> 6, lane = tid & 63;
  __shared__ __align__(16) unsigned short sBT[kDS * kWS];
  __shared__ __align__(16) unsigned short sxd[kCS * kWS];
  __shared__ float s_dt[kCS];
  __shared__ float s_acum[kCS];
  const int l0 = b * kL + c * kCS;
  if (tid < kCS) s_dt[tid] = dtbuf[(size_t)(l0 + tid) * kNH + h];
  __syncthreads();
  if (tid == 0) {
    float A = -expf(A_log[h]);
    float run = 0.f;
    for (int s = 0; s < kCS; s++) { run += A * s_dt[s]; s_acum[s] = run; }
    asum[id] = run;
  }
  __syncthreads();
  const float total = s_acum[kCS - 1];
  for (int e = tid; e < kCS * kDS; e += 256) {
    int s = e >> 7, n = e & 127;
    sBT[n * kWS + s] = xbc_act[(size_t)(l0 + s) * kConvDim + kDI + n];
  }
  for (int e = tid; e < kCS * kHP; e += 256) {
    int s = e >> 6, p = e & 63;
    float xv = bu2f(xbc_act[(size_t)(l0 + s) * kConvDim + h * kHP + p]);
    sxd[p * kWS + s] = f2bu(xv * s_dt[s] * expf(total - s_acum[s]));
  }
  __syncthreads();
  const int arow = wave * 16 + (lane & 15);
  const int fk = (lane >> 4) * 8;
  f32x4 acc[8] = {};
#pragma unroll
  for (int kk = 0; kk < 2; kk++) {
    bf16x8 a = *(const bf16x8*)&sxd[arow * kWS + kk * 32 + fk];
#pragma unroll
    for (int j = 0; j < 8; j++) {
      bf16x8 bb = *(const bf16x8*)&sBT[(j * 16 + (lane & 15)) * kWS + kk * 32 + fk];
      acc[j] = __builtin_amdgcn_mfma_f32_16x16x32_bf16(a, bb, acc[j], 0, 0, 0);
    }
  }
  const int prow = wave * 16 + (lane >> 4) * 4;
  const int ncol = lane & 15;
  size_t base = (size_t)id * (kHP * kDS);
#pragma unroll
  for (int j = 0; j < 8; j++)
#pragma unroll
    for (int r = 0; r < 4; r++)
      states[base + (size_t)(prow + r) * kDS + j * 16 + ncol] = f2bu(acc[j][r]);
}

// ---- K5: sequential inter-chunk scan with software prefetch
__global__ void scan_kernel(unsigned short* __restrict__ states,
                            const float* __restrict__ asum) {
  const int blk = blockIdx.x;
  const int seg = blk & 7;
  const int bh = blk >> 3;
  const int h = bh & 31, b = bh >> 5;
  const int e4 = seg * 256 + threadIdx.x;
  const size_t cstride = (size_t)kNH * 2048;            // ushort4 units per chunk
  ushort4* p = (ushort4*)states + ((size_t)(b * kNC) * kNH + h) * 2048 + e4;
  const float* ap = asum + (b * kNC) * kNH + h;
  float c0 = 0.f, c1 = 0.f, c2 = 0.f, c3 = 0.f;
  ushort4 t = p[0];
  float dec = expf(ap[0]);
  for (int c = 0; c < kNC; c++) {
    ushort4 tn = t;
    float decn = dec;
    if (c + 1 < kNC) {                                  // prefetch next chunk
      tn = p[(size_t)(c + 1) * cstride];
      decn = expf(ap[(c + 1) * kNH]);
    }
    ushort4 o;
    o.x = f2bu(c0); o.y = f2bu(c1); o.z = f2bu(c2); o.w = f2bu(c3);
    p[(size_t)c * cstride] = o;
    c0 = c0 * dec + bu2f(t.x);
    c1 = c1 * dec + bu2f(t.y);
    c2 = c2 * dec + bu2f(t.z);
    c3 = c3 * dec + bu2f(t.w);
    t = tn; dec = decn;
  }
}

// ---- K6: intra-chunk Y, 4 heads/block (round-6 version: Sin staged via LDS)
__global__ __launch_bounds__(256) void y_kernel(
    const unsigned short* __restrict__ xbc_act,
    const unsigned short* __restrict__ zxbcdt,
    const unsigned short* __restrict__ states_in,
    const float* __restrict__ dtbuf,
    const float* __restrict__ A_log,
    unsigned short* __restrict__ ybuf,
    float* __restrict__ pS, float* __restrict__ pQ) {
  const int id = blockIdx.x;                 // (b*NC + c)*8 + hg
  const int hg = id & 7;
  const int c = (id >> 3) & (kNC - 1);
  const int b = id >> 9;
  const int tid = threadIdx.x;
  const int wave = tid >> 6, lane = tid & 63;
  __shared__ __align__(16) unsigned short sC[kCS * kTS];
  __shared__ __align__(16) unsigned short sB[kCS * kTS];
  __shared__ __align__(16) unsigned short sxd[kCS * kWS];
  __shared__ __align__(16) unsigned short sW[kCS * kWS];
  __shared__ float s_dt[4][kCS];
  __shared__ float s_acum[4][kCS];
  const int l0 = b * kL + c * kCS;
  {
    int hh = tid >> 6, s = tid & 63;
    s_dt[hh][s] = dtbuf[(size_t)(l0 + s) * kNH + hg * 4 + hh];
  }
  __syncthreads();
  if (tid < 4) {
    float A = -expf(A_log[hg * 4 + tid]);
    float run = 0.f;
    for (int s = 0; s < kCS; s++) { run += A * s_dt[tid][s]; s_acum[tid][s] = run; }
  }
  for (int e = tid; e < kCS * 16; e += 256) {
    int row = e >> 4, c8 = (e & 15) * 8;
    size_t rb = (size_t)(l0 + row) * kConvDim;
    *(ushort8*)&sB[row * kTS + c8] = *(const ushort8*)&xbc_act[rb + kDI + c8];
    *(ushort8*)&sC[row * kTS + c8] = *(const ushort8*)&xbc_act[rb + kDI + kDS + c8];
  }
  __syncthreads();
  const int arow = wave * 16 + (lane & 15);
  const int fk = (lane >> 4) * 8;
  // G[l][s] = C . B^T  (K=128) — head-independent, once per block
  f32x4 accG[4] = {};
#pragma unroll
  for (int kk = 0; kk < 4; kk++) {
    bf16x8 a = *(const bf16x8*)&sC[arow * kTS + kk * 32 + fk];
#pragma unroll
    for (int j = 0; j < 4; j++) {
      bf16x8 bb = *(const bf16x8*)&sB[(j * 16 + (lane & 15)) * kTS + kk * 32 + fk];
      accG[j] = __builtin_amdgcn_mfma_f32_16x16x32_bf16(a, bb, accG[j], 0, 0, 0);
    }
  }
  const int lrow = wave * 16 + (lane >> 4) * 4;
  const size_t sbase = (size_t)((b * kNC + c) * kNH) * (kHP * kDS);
  float rS[4] = {}, rQ[4] = {};
  for (int hh = 0; hh < 4; hh++) {
    const int h = hg * 4 + hh;
    __syncthreads();   // prior iteration (or G) done reading sB/sxd/sW
    // stage xd^T for this head
    for (int e = tid; e < kCS * kHP; e += 256) {
      int s = e >> 6, p = e & 63;
      float xv = bu2f(xbc_act[(size_t)(l0 + s) * kConvDim + h * kHP + p]);
      sxd[p * kWS + s] = f2bu(xv * s_dt[hh][s]);
    }
    // W = mask(G)*decay  (wave-local strip)
#pragma unroll
    for (int j = 0; j < 4; j++) {
      int scol = j * 16 + (lane & 15);
      float as = s_acum[hh][scol];
#pragma unroll
      for (int r = 0; r < 4; r++) {
        int l = lrow + r;
        float w = (scol <= l) ? accG[j][r] * expf(s_acum[hh][l] - as) : 0.f;
        sW[l * kWS + scol] = f2bu(w);
      }
    }
    // stage Sin[p][n] for this head into sB
    for (int e = tid; e < kCS * 16; e += 256) {
      int row = e >> 4, c8 = (e & 15) * 8;
      *(ushort8*)&sB[row * kTS + c8] =
          *(const ushort8*)&states_in[sbase + (size_t)h * (kHP * kDS) + row * kDS + c8];
    }
    __syncthreads();
    // Yd = W . xd^T  (K=64)
    f32x4 accY[4] = {};
#pragma unroll
    for (int kk = 0; kk < 2; kk++) {
      bf16x8 a = *(const bf16x8*)&sW[arow * kWS + kk * 32 + fk];
#pragma unroll
      for (int j = 0; j < 4; j++) {
        bf16x8 bb = *(const bf16x8*)&sxd[(j * 16 + (lane & 15)) * kWS + kk * 32 + fk];
        accY[j] = __builtin_amdgcn_mfma_f32_16x16x32_bf16(a, bb, accY[j], 0, 0, 0);
      }
    }
    // Yoff = C . Sin^T  (K=128)
    f32x4 accO[4] = {};
#pragma unroll
    for (int kk = 0; kk < 4; kk++) {
      bf16x8 a = *(const bf16x8*)&sC[arow * kTS + kk * 32 + fk];
#pragma unroll
      for (int j = 0; j < 4; j++) {
        bf16x8 bb = *(const bf16x8*)&sB[(j * 16 + (lane & 15)) * kTS + kk * 32 + fk];
        accO[j] = __builtin_amdgcn_mfma_f32_16x16x32_bf16(a, bb, accO[j], 0, 0, 0);
      }
    }
#pragma unroll
    for (int r = 0; r < 4; r++) {
      int l = lrow + r;
      float el = expf(s_acum[hh][l]);
      size_t zrow = (size_t)(l0 + l) * kDProj + h * kHP;
      size_t yrow = (size_t)(l0 + l) * kDI + h * kHP;
#pragma unroll
      for (int j = 0; j < 4; j++) {
        int p = j * 16 + (lane & 15);
        float yv = accY[j][r] + el * accO[j][r];
        float z = bu2f(zxbcdt[zrow + p]);
        yv *= z / (1.f + expf(-z));
        rS[r] += yv;
        rQ[r] += yv * yv;
        ybuf[yrow + p] = f2bu(yv);
      }
    }
  }
#pragma unroll
  for (int m = 1; m < 16; m <<= 1) {
#pragma unroll
    for (int r = 0; r < 4; r++) {
      rS[r] += __shfl_xor(rS[r], m);
      rQ[r] += __shfl_xor(rQ[r], m);
    }
  }
  if ((lane & 15) == 0) {
#pragma unroll
    for (int r = 0; r < 4; r++) {
      int row = l0 + lrow + r;
      pS[(size_t)row * 8 + hg] = rS[r];
      pQ[(size_t)row * 8 + hg] = rQ[r];
    }
  }
}

// ---- K7: finalize LN stats from per-block partials
__global__ void ln_reduce(const float* __restrict__ pS, const float* __restrict__ pQ,
                          float* __restrict__ mu, float* __restrict__ rstd) {
  int row = blockIdx.x * 256 + threadIdx.x;
  if (row >= kRows) return;
  float s = 0.f, q = 0.f;
#pragma unroll
  for (int i = 0; i < 8; i++) { s += pS[(size_t)row * 8 + i]; q += pQ[(size_t)row * 8 + i]; }
  float m = s / kDI;
  mu[row] = m;
  rstd[row] = rsqrtf(q / kDI - m * m + kEps);
}

}  // namespace

extern "C" void kernel_launch(void* const* d_in, const int* in_sizes, int n_in,
                              void* d_out, int out_size, void* d_ws, size_t ws_size,
                              hipStream_t stream) {
  const float* u       = (const float*)d_in[0];
  const float* W_in    = (const float*)d_in[1];
  const float* conv_w  = (const float*)d_in[2];
  const float* conv_b  = (const float*)d_in[3];
  const float* dt_bias = (const float*)d_in[4];
  const float* A_log   = (const float*)d_in[5];
  const float* norm_w  = (const float*)d_in[6];
  const float* norm_b  = (const float*)d_in[7];
  const float* W_out   = (const float*)d_in[8];
  float* out = (float*)d_out;

  char* ws = (char*)d_ws;
  size_t off = 0;
  auto alloc = [&](size_t bytes) {
    void* p = ws + off;
    off += (bytes + 255) & ~(size_t)255;
    return p;
  };
  unsigned short* zxbcdt = (unsigned short*)alloc((size_t)kRows * kDProj * 2);        // 71.8 MB
  unsigned short* xbc    = (unsigned short*)alloc((size_t)kRows * kConvDim * 2);      // 37.7 MB
  float* dtb             = (float*)alloc((size_t)kRows * kNH * 4);                    //  1.0 MB
  float* asum            = (float*)alloc((size_t)kB * kNC * kNH * 4);                 // 16 KB
  unsigned short* A1     = (unsigned short*)alloc((size_t)kRows * 1024 * 2);          // 16.8 MB
  unsigned short* Bt1    = (unsigned short*)alloc((size_t)kDProjP * 1024 * 2);        //  9.2 MB
  unsigned short* states = (unsigned short*)alloc((size_t)kB * kNC * kNH * kHP * kDS * 2); // 67.1 MB
  unsigned short* Bt2    = (unsigned short*)alloc((size_t)1024 * kDI * 2);            //  4.2 MB
  unsigned short* ybuf   = (unsigned short*)alloc((size_t)kRows * kDI * 2);           // 33.6 MB
  float* mu              = (float*)alloc((size_t)kRows * 4);
  float* rstd            = (float*)alloc((size_t)kRows * 4);
  float* t1              = (float*)alloc(1024 * 4);
  float* t2              = (float*)alloc(1024 * 4);
  float* pS              = (float*)alloc((size_t)kRows * 8 * 4);                      // 256 KB
  float* pQ              = (float*)alloc((size_t)kRows * 8 * 4);                      // 256 KB
  (void)ws_size; (void)in_sizes; (void)n_in; (void)out_size;

  cast_kernel<<<(kRows * 1024 / 4 + 255) / 256, 256, 0, stream>>>(
      (const float4*)u, (ushort4*)A1, kRows * 1024 / 4);
  transpose_cast<<<dim3(kDProjP / 32, 1024 / 32), 256, 0, stream>>>(
      W_in, Bt1, 1024, kDProj, nullptr);
  transpose_cast<<<dim3(1024 / 32, 2048 / 32), 256, 0, stream>>>(
      W_out, Bt2, 2048, 1024, norm_w);
  colsum_kernel<<<16, 256, 0, stream>>>(W_out, norm_w, norm_b, t1, t2);
  gemm_bt<unsigned short, false><<<dim3(kDProjP / 128, kRows / 128), 256, 0, stream>>>(
      A1, Bt1, zxbcdt, kRows, kDProj, 1024, nullptr, nullptr, nullptr, nullptr);
  dt_kernel<<<(kRows * kNH + 255) / 256, 256, 0, stream>>>(zxbcdt, dt_bias, dtb);
  conv_silu_kernel<<<dim3(3, kRows / 8), 256, 0, stream>>>(zxbcdt, conv_w, conv_b, xbc);
  chunk_state_kernel<<<kB * kNC * kNH, 256, 0, stream>>>(xbc, dtb, A_log, states, asum);
  scan_kernel<<<kB * kNH * 8, 256, 0, stream>>>(states, asum);
  y_kernel<<<kB * kNC * 8, 256, 0, stream>>>(xbc, zxbcdt, states, dtb, A_log, ybuf, pS, pQ);
  ln_reduce<<<kRows / 256, 256, 0, stream>>>(pS, pQ, mu, rstd);
  gemm_bt<float, true><<<dim3(1024 / 128, kRows / 128), 256, 0, stream>>>(
      ybuf, Bt2, out, kRows, 1024, 2048, mu, rstd, t1, t2);
}